// Round 11
// baseline (232.885 us; speedup 1.0000x reference)
//
#include <hip/hip_runtime.h>
#include <hip/hip_bf16.h>
#include <cstdint>
#include <cstddef>

typedef __hip_bfloat16 bf16;
typedef __attribute__((ext_vector_type(8))) short short8;
typedef __attribute__((ext_vector_type(4))) float f32x4;
typedef __attribute__((ext_vector_type(16))) float f32x16;

#define C_EMBD 768
#define C3     2304
#define T_SEQ  4096
#define NHEAD  12
#define KVSPLIT 2

// ---------------------------------------------------------------- helpers
__device__ __forceinline__ void load16(const void* g, void* lds) {
  __builtin_amdgcn_global_load_lds(
      (const __attribute__((address_space(1))) uint32_t*)g,
      (__attribute__((address_space(3))) uint32_t*)lds, 16, 0, 0);
}

__device__ __forceinline__ short f2bf_bits(float x) {
  union { bf16 h; short s; } u; u.h = __float2bfloat16(x); return u.s;
}

__device__ __forceinline__ float bfbits2f(short s) {
  union { uint32_t u; float f; } u; u.u = ((uint32_t)(unsigned short)s) << 16; return u.f;
}

__device__ __forceinline__ float max3f(float a, float b, float c) {
  float d;
  asm("v_max3_f32 %0, %1, %2, %3" : "=v"(d) : "v"(a), "v"(b), "v"(c));
  return d;
}

// exp in log2-domain when native exp2 builtin is available (folds log2e into Q scale)
#if __has_builtin(__builtin_amdgcn_exp2f)
#define QK_SCALE (0.125f * 1.44269504088896340736f)
__device__ __forceinline__ float expx(float x) { return __builtin_amdgcn_exp2f(x); }
#else
#define QK_SCALE 0.125f
__device__ __forceinline__ float expx(float x) { return __expf(x); }
#endif

// ---------------------------------------------------------------- LN2 fused with ao split-K combine:
// xv = pa0 + pa1 + x + b_ao ; x1 = xv ; out = bf16(LN(xv))
__global__ __launch_bounds__(256) void ln2_fused_kernel(
    const float* __restrict__ pa0, const float* __restrict__ pa1,
    const float* __restrict__ x, const float* __restrict__ b_ao,
    const float* __restrict__ g, const float* __restrict__ b,
    bf16* __restrict__ out, float* __restrict__ x1) {
  const int row = blockIdx.x;
  const int tid = threadIdx.x;
  const int lane = tid & 63, wave = tid >> 6;
  float v[3];
  #pragma unroll
  for (int i = 0; i < 3; ++i) {
    const int c = tid + i * 256;
    const size_t idx = (size_t)row * C_EMBD + c;
    v[i] = pa0[idx] + pa1[idx] + x[idx] + b_ao[c];
    x1[idx] = v[i];
  }
  float s = v[0] + v[1] + v[2];
  #pragma unroll
  for (int o = 1; o < 64; o <<= 1) s += __shfl_xor(s, o, 64);
  __shared__ float red[4];
  if (lane == 0) red[wave] = s;
  __syncthreads();
  const float mu = (red[0] + red[1] + red[2] + red[3]) * (1.0f / C_EMBD);
  float d0 = v[0] - mu, d1 = v[1] - mu, d2 = v[2] - mu;
  float q = d0 * d0 + d1 * d1 + d2 * d2;
  #pragma unroll
  for (int o = 1; o < 64; o <<= 1) q += __shfl_xor(q, o, 64);
  __syncthreads();
  if (lane == 0) red[wave] = q;
  __syncthreads();
  const float var = (red[0] + red[1] + red[2] + red[3]) * (1.0f / C_EMBD);
  const float rs = rsqrtf(var + 1e-5f);
  #pragma unroll
  for (int i = 0; i < 3; ++i) {
    int c = tid + i * 256;
    out[(size_t)row * C_EMBD + c] = __float2bfloat16((v[i] - mu) * rs * g[c] + b[c]);
  }
}

// ---------------------------------------------------------------- fused 4x transpose + ln1
// blocks 0..6911: weight transposes fp32 [R][C] -> bf16 [C][R]
// blocks 6912..11007: ln1 rows (4096) — h = bf16(LN(x))
__global__ __launch_bounds__(256) void transpose4_ln_kernel(
    const float* __restrict__ wA, bf16* __restrict__ oA,
    const float* __restrict__ wB, bf16* __restrict__ oB,
    const float* __restrict__ wC, bf16* __restrict__ oC,
    const float* __restrict__ wD, bf16* __restrict__ oD,
    const float* __restrict__ x, const float* __restrict__ lg,
    const float* __restrict__ lb, bf16* __restrict__ oh) {
  __shared__ float tile[32][33];
  __shared__ float red[4];
  int b = blockIdx.x;
  if (b >= 6912) {
    // ---- LN1 path
    const int row = b - 6912;
    const int tid = threadIdx.y * 32 + threadIdx.x;
    const int lane = tid & 63, wave = tid >> 6;
    const float* xr = x + (size_t)row * C_EMBD;
    float v[3];
    #pragma unroll
    for (int i = 0; i < 3; ++i) v[i] = xr[tid + i * 256];
    float s = v[0] + v[1] + v[2];
    #pragma unroll
    for (int o = 1; o < 64; o <<= 1) s += __shfl_xor(s, o, 64);
    if (lane == 0) red[wave] = s;
    __syncthreads();
    const float mu = (red[0] + red[1] + red[2] + red[3]) * (1.0f / C_EMBD);
    float d0 = v[0] - mu, d1 = v[1] - mu, d2 = v[2] - mu;
    float q = d0 * d0 + d1 * d1 + d2 * d2;
    #pragma unroll
    for (int o = 1; o < 64; o <<= 1) q += __shfl_xor(q, o, 64);
    __syncthreads();
    if (lane == 0) red[wave] = q;
    __syncthreads();
    const float var = (red[0] + red[1] + red[2] + red[3]) * (1.0f / C_EMBD);
    const float rs = rsqrtf(var + 1e-5f);
    #pragma unroll
    for (int i = 0; i < 3; ++i) {
      int c = tid + i * 256;
      oh[(size_t)row * C_EMBD + c] = __float2bfloat16((v[i] - mu) * rs * lg[c] + lb[c]);
    }
    return;
  }
  // ---- transpose path
  const float* in; bf16* out; int R, C;
  if (b < 1728)      { in = wA; out = oA; R = 768;  C = 2304; }
  else if (b < 2304) { b -= 1728; in = wB; out = oB; R = 768;  C = 768;  }
  else if (b < 4608) { b -= 2304; in = wC; out = oC; R = 768;  C = 3072; }
  else               { b -= 4608; in = wD; out = oD; R = 3072; C = 768;  }
  const int ntx = C / 32;
  const int bx = (b % ntx) * 32;  // col in 'in'
  const int by = (b / ntx) * 32;  // row in 'in'
  const int tx = threadIdx.x, ty = threadIdx.y;
  #pragma unroll
  for (int i = 0; i < 32; i += 8)
    tile[ty + i][tx] = in[(size_t)(by + ty + i) * C + bx + tx];
  __syncthreads();
  #pragma unroll
  for (int i = 0; i < 32; i += 8)
    out[(size_t)(bx + ty + i) * R + by + tx] = __float2bfloat16(tile[tx][ty + i]);
}

// ---------------------------------------------------------------- GEMM: A[M][K] bf16 x BT[N][K] bf16
// 2-phase double-buffered K-loop; 32x32x16 MFMA inner with a row-bit1 XOR LDS swizzle.
// Bank analysis: unswizzled, the 32x32 A-fragment read (rows 0..31 x 32B slice at
// 64B row stride) touches only 16 of 32 banks (2x conflict). Swizzle: LDS row r's two
// 32B halves are swapped when (r>>1)&1 — applied as inverse-permuted GLOBAL source
// (scol ^= 16 shorts) + XOR on the ds_read offset (rule: both-sides-or-neither with
// global_load_lds's linear dest). Rows 0-3 then cover all 32 banks -> conflict-free.
// Fragment mapping (HW-verified m74/m101, in use by attn QK^T):
//   A-operand lane l: row = l&31, k = (l>>5)*8 + j
//   C/D lane l, reg r: col = l&31, row = (r&3) + 8*(r>>2) + 4*(l>>5)
// EPI 0: out = bf16(acc + bias)
// EPI 2: out = bf16(gelu(acc + bias))
// EPI 4: split-K over blockIdx.z (deterministic): z==0 -> outp, z==1 -> outp2, raw f32 acc
template <int EPI>
__global__ __launch_bounds__(256, 3) void gemm_bt(
    const bf16* __restrict__ A, const bf16* __restrict__ BT,
    const float* __restrict__ bias, const float* __restrict__ res,
    void* __restrict__ outp, float* __restrict__ outp2, int M, int N, int Ks, int Kst) {
  __shared__ __align__(16) short sA[2][128 * 32];
  __shared__ __align__(16) short sB[2][128 * 32];
  const int tid = threadIdx.x;
  const int wave = tid >> 6, lane = tid & 63;
  const int col32 = lane & 31, khalf = lane >> 5;
  const int wr = wave >> 1, wc = wave & 1;
  const int tM = blockIdx.y * 128, tN = blockIdx.x * 128;
  const int z = (EPI == 4) ? blockIdx.z : 0;

  f32x16 acc[2][2] = {};

  const int srow = tid >> 2;
  // inverse-swizzled global source column: 16-short (32B) halves of each 64B row are
  // swapped when (srow>>1)&1, so linear global_load_lds lands them pre-swizzled.
  const int scol = ((tid & 3) * 8) ^ ((((srow) >> 1) & 1) << 4);
  const bf16* gA = A + (size_t)z * Ks + (size_t)(tM + srow) * Kst + scol;
  const bf16* gB = BT + (size_t)z * Ks + (size_t)(tN + srow) * Kst + scol;
  const int woff = wave * 1024;
  const size_t rowskip = (size_t)64 * Kst;

  // swizzled read offset (shorts): same XOR keyed on the fragment row (col32)
  const int rdswz = ((col32 >> 1) & 1) << 4;

  const int nk = Ks >> 5;
  // prologue: stage k-step 0 into buffer 0
  {
    char* la = (char*)sA[0] + woff;
    char* lb = (char*)sB[0] + woff;
    load16(gA, la);
    load16(gA + rowskip, la + 4096);
    load16(gB, lb);
    load16(gB + rowskip, lb + 4096);
    gA += 32; gB += 32;
  }
  __syncthreads();  // prologue loads drained

  int cur = 0;
  for (int k0 = 0; k0 < nk; ++k0) {
    // issue stage of k-step k0+1 into the other buffer (overlaps compute below)
    if (k0 + 1 < nk) {
      char* la = (char*)sA[cur ^ 1] + woff;
      char* lb = (char*)sB[cur ^ 1] + woff;
      load16(gA, la);
      load16(gA + rowskip, la + 4096);
      load16(gB, lb);
      load16(gB + rowskip, lb + 4096);
      gA += 32; gB += 32;
    }
    // compute from buffer cur: 2x2 32x32 tiles, K=32 as two K=16 chains
    const short* bufA = sA[cur];
    const short* bufB = sB[cur];
    short8 a[2][2], bb[2][2];
    #pragma unroll
    for (int mi = 0; mi < 2; ++mi)
      #pragma unroll
      for (int kh = 0; kh < 2; ++kh) {
        const int off = (kh * 16 + khalf * 8) ^ rdswz;
        a[mi][kh]  = *(const short8*)&bufA[(wr * 64 + mi * 32 + col32) * 32 + off];
        bb[mi][kh] = *(const short8*)&bufB[(wc * 64 + mi * 32 + col32) * 32 + off];
      }
    #pragma unroll
    for (int mi = 0; mi < 2; ++mi)
      #pragma unroll
      for (int ni = 0; ni < 2; ++ni) {
        acc[mi][ni] = __builtin_amdgcn_mfma_f32_32x32x16_bf16(a[mi][0], bb[ni][0], acc[mi][ni], 0, 0, 0);
        acc[mi][ni] = __builtin_amdgcn_mfma_f32_32x32x16_bf16(a[mi][1], bb[ni][1], acc[mi][ni], 0, 0, 0);
      }
    __syncthreads();  // all waves done reading cur; next-buffer stage drained
    cur ^= 1;
  }

  bf16* outh = (bf16*)outp;
  float* po = (EPI == 4) ? ((z == 0) ? (float*)outp : outp2) : nullptr;
  #pragma unroll
  for (int mi = 0; mi < 2; ++mi) {
    #pragma unroll
    for (int ni = 0; ni < 2; ++ni) {
      const int col = tN + wc * 64 + ni * 32 + col32;
      const float bv = (EPI == 4) ? 0.f : bias[col];
      #pragma unroll
      for (int r = 0; r < 16; ++r) {
        const int row = tM + wr * 64 + mi * 32 + (r & 3) + 8 * (r >> 2) + 4 * khalf;
        const size_t idx = (size_t)row * N + col;
        float v = acc[mi][ni][r] + bv;
        if constexpr (EPI == 4) {
          po[idx] = v;
        } else if constexpr (EPI == 2) {
          v = 0.5f * v * (1.0f + erff(v * 0.70710678118654752f));
          outh[idx] = __float2bfloat16(v);
        } else {
          outh[idx] = __float2bfloat16(v);
        }
      }
    }
  }
  (void)res;
}

// ---------------------------------------------------------------- split-K combine: out = p0+p1+res+bias
// (p0 may alias out: each thread reads its element before writing it)
__global__ __launch_bounds__(256) void splitk_combine(const float* p0,
    const float* __restrict__ p1, const float* __restrict__ res,
    const float* __restrict__ bias, float* out) {
  const int row = blockIdx.x;
  const int tid = threadIdx.x;
  #pragma unroll
  for (int i = 0; i < 3; ++i) {
    const int c = tid + i * 256;
    const size_t idx = (size_t)row * C_EMBD + c;
    out[idx] = p0[idx] + p1[idx] + res[idx] + bias[c];
  }
}

// ---------------------------------------------------------------- flash attention fwd (no mask), v6 (round-4/6 best)
// Swapped QK^T 32x32x16, in-register softmax, KVSPLIT=2, delayed-PV pipeline.
// Grid: (T/128, NHEAD, KVSPLIT), block 256 (4 waves x 32 q-rows).
__global__ __launch_bounds__(256, 2) void attn_kernel(const bf16* __restrict__ qkv,
                                                      float* __restrict__ pacc,
                                                      float* __restrict__ pml) {
  __shared__ __align__(16) char sKb[2 * 8192];
  __shared__ __align__(16) char sVb[2 * 8192];
  __shared__ float sRed[4 * 32];

  const int tid = threadIdx.x;
  const int wave = tid >> 6, lane = tid & 63;
  const int qi = lane & 31;
  const int hi = lane >> 5;
  const int hi16 = hi * 16;
  const int head = blockIdx.y;
  const int z = blockIdx.z;
  const int qw = blockIdx.x * 128 + wave * 32;

  short8 qf[4];
  {
    const bf16* qrow = qkv + (size_t)(qw + qi) * C3 + head * 64;
    #pragma unroll
    for (int kd = 0; kd < 4; ++kd) {
      short8 v = *(const short8*)(qrow + kd * 16 + hi * 8);
      #pragma unroll
      for (int i = 0; i < 8; ++i) v[i] = f2bf_bits(bfbits2f(v[i]) * QK_SCALE);
      qf[kd] = v;
    }
  }

  f32x16 acc0 = {}, acc1 = {};
  float m = -3.0e38f, l = 0.f;
  short8 pfrag[4];

  const int nt = (T_SEQ / 64) / KVSPLIT;
  const size_t tilestep = (size_t)64 * C3;
  const size_t zoff = (size_t)z * nt * tilestep;
  const int ksrow = tid >> 3;
  const int kswz = ((tid & 7) ^ (ksrow & 7)) * 8;
  const bf16* gk_base = qkv + zoff + (size_t)ksrow * C3 + C_EMBD + head * 64 + kswz;
  const int vp = tid & 31;
  const int vd0 = (tid >> 5) * 8;
  const bf16* gv_base = qkv + zoff + (size_t)(2 * vp) * C3 + 2 * C_EMBD + head * 64 + vd0;

  const int krow0 = qi * 128;
  const int krow_swz = (qi & 7) << 4;
  const int d1 = 32 + qi;
  const int vs0 = ((qi & 7) ^ ((qi >> 3) & 7)) << 4;
  const int vs1 = ((d1 & 7) ^ ((d1 >> 3) & 7)) << 4;

  short8 v0 = *(const short8*)gv_base;
  short8 v1 = *(const short8*)(gv_base + C3);
  load16(gk_base, sKb + wave * 1024);
  load16(gk_base + (size_t)32 * C3, sKb + wave * 1024 + 4096);

  for (int t = 0; t < nt; ++t) {
    const int cur = t & 1;
    char* bK = sKb + cur * 8192;
    char* bV = sVb + cur * 8192;

    __syncthreads();

    #pragma unroll
    for (int j = 0; j < 8; ++j) {
      const int d = vd0 + j;
      const int vs = ((d & 7) ^ ((d >> 3) & 7)) << 4;
      const uint32_t packed = (uint32_t)(unsigned short)v0[j] |
                              ((uint32_t)(unsigned short)v1[j] << 16);
      *(uint32_t*)(bV + d * 128 + ((vp * 4) ^ vs)) = packed;
    }

    if (t + 1 < nt) {
      const bf16* gv = gv_base + (size_t)(t + 1) * tilestep;
      v0 = *(const short8*)gv;
      v1 = *(const short8*)(gv + C3);
      const bf16* gk = gk_base + (size_t)(t + 1) * tilestep;
      char* bKn = sKb + (cur ^ 1) * 8192;
      load16(gk, bKn + wave * 1024);
      load16(gk + (size_t)32 * C3, bKn + wave * 1024 + 4096);
    }

    f32x16 s0 = {}, s1 = {};
    __builtin_amdgcn_s_setprio(1);
    #pragma unroll
    for (int kd = 0; kd < 4; ++kd) {
      const int off = (kd * 32 + hi16) ^ krow_swz;
      short8 ka0 = *(const short8*)(bK + krow0 + off);
      short8 ka1 = *(const short8*)(bK + 4096 + krow0 + off);
      s0 = __builtin_amdgcn_mfma_f32_32x32x16_bf16(ka0, qf[kd], s0, 0, 0, 0);
      s1 = __builtin_amdgcn_mfma_f32_32x32x16_bf16(ka1, qf[kd], s1, 0, 0, 0);
    }

    if (t > 0) {
      char* bVp = sVb + (cur ^ 1) * 8192;
      #pragma unroll
      for (int kk = 0; kk < 4; ++kk) {
        const int voff = (kk * 32 + hi16);
        short8 vb0 = *(const short8*)(bVp + qi * 128 + (voff ^ vs0));
        short8 vb1 = *(const short8*)(bVp + d1 * 128 + (voff ^ vs1));
        acc0 = __builtin_amdgcn_mfma_f32_32x32x16_bf16(pfrag[kk], vb0, acc0, 0, 0, 0);
        acc1 = __builtin_amdgcn_mfma_f32_32x32x16_bf16(pfrag[kk], vb1, acc1, 0, 0, 0);
      }
    }
    __builtin_amdgcn_s_setprio(0);

    float t8[8];
    #pragma unroll
    for (int i = 0; i < 8; ++i) t8[i] = max3f(s0[i], s0[i + 8], s1[i]);
    float t4[4];
    #pragma unroll
    for (int i = 0; i < 4; ++i) t4[i] = max3f(t8[2 * i], t8[2 * i + 1], s1[8 + i]);
    float t2[2];
    #pragma unroll
    for (int i = 0; i < 2; ++i) t2[i] = max3f(t4[2 * i], t4[2 * i + 1], s1[12 + i]);
    const float t1 = max3f(t2[0], t2[1], s1[14]);
    const float tmx = fmaxf(t1, s1[15]);
    float pmax;
    {
      float a0 = tmx, a1 = tmx;
      asm("v_permlane32_swap_b32 %0, %1" : "+v"(a0), "+v"(a1));
      pmax = fmaxf(a0, a1);
    }

    if (__any(pmax - m > 8.0f)) {
      const float mn = fmaxf(m, pmax);
      const float sc = expx(m - mn);
      l *= sc;
      if (lane < 32) sRed[wave * 32 + qi] = sc;
      #pragma unroll
      for (int r = 0; r < 16; ++r) {
        const float sv = sRed[wave * 32 + ((r & 3) + 8 * (r >> 2) + hi * 4)];
        acc0[r] *= sv; acc1[r] *= sv;
      }
      m = mn;
    }

    float red[16];
    #pragma unroll
    for (int r = 0; r < 16; ++r) { s0[r] = expx(s0[r] - m); s1[r] = expx(s1[r] - m); }
    #pragma unroll
    for (int r = 0; r < 16; ++r) red[r] = s0[r] + s1[r];
    #pragma unroll
    for (int w = 8; w >= 1; w >>= 1)
      #pragma unroll
      for (int r = 0; r < w; ++r) red[r] += red[r + w];
    {
      float a0 = red[0], a1 = red[0];
      asm("v_permlane32_swap_b32 %0, %1" : "+v"(a0), "+v"(a1));
      l += a0 + a1;
    }

    #pragma unroll
    for (int b = 0; b < 2; ++b) {
      const f32x16 sb = b ? s1 : s0;
      uint32_t pk[8];
      #pragma unroll
      for (int g = 0; g < 4; ++g) {
        asm("v_cvt_pk_bf16_f32 %0, %1, %2" : "=v"(pk[2 * g])     : "v"(sb[4 * g + 0]), "v"(sb[4 * g + 1]));
        asm("v_cvt_pk_bf16_f32 %0, %1, %2" : "=v"(pk[2 * g + 1]) : "v"(sb[4 * g + 2]), "v"(sb[4 * g + 3]));
      }
      #pragma unroll
      for (int kbl = 0; kbl < 2; ++kbl) {
        uint32_t w0 = pk[4 * kbl + 0], w2 = pk[4 * kbl + 2];
        asm("v_permlane32_swap_b32 %0, %1" : "+v"(w0), "+v"(w2));
        uint32_t w1 = pk[4 * kbl + 1], w3 = pk[4 * kbl + 3];
        asm("v_permlane32_swap_b32 %0, %1" : "+v"(w1), "+v"(w3));
        union { uint32_t u[4]; short8 v; } pu;
        pu.u[0] = w0; pu.u[1] = w1; pu.u[2] = w2; pu.u[3] = w3;
        pfrag[b * 2 + kbl] = pu.v;
      }
    }
  }

  __syncthreads();
  {
    char* bVl = sVb + ((nt - 1) & 1) * 8192;
    __builtin_amdgcn_s_setprio(1);
    #pragma unroll
    for (int kk = 0; kk < 4; ++kk) {
      const int voff = (kk * 32 + hi16);
      short8 vb0 = *(const short8*)(bVl + qi * 128 + (voff ^ vs0));
      short8 vb1 = *(const short8*)(bVl + d1 * 128 + (voff ^ vs1));
      acc0 = __builtin_amdgcn_mfma_f32_32x32x16_bf16(pfrag[kk], vb0, acc0, 0, 0, 0);
      acc1 = __builtin_amdgcn_mfma_f32_32x32x16_bf16(pfrag[kk], vb1, acc1, 0, 0, 0);
    }
    __builtin_amdgcn_s_setprio(0);
  }

  float* pa = pacc + ((size_t)z * T_SEQ + qw) * C_EMBD + head * 64;
  #pragma unroll
  for (int r = 0; r < 16; ++r) {
    const int q = (r & 3) + 8 * (r >> 2) + hi * 4;
    pa[(size_t)q * C_EMBD + qi]      = acc0[r];
    pa[(size_t)q * C_EMBD + 32 + qi] = acc1[r];
  }
  if (lane < 32) {
    float2* mlp = (float2*)pml;
    mlp[((size_t)z * NHEAD + head) * T_SEQ + qw + qi] = make_float2(m, l);
  }
}

// ---------------------------------------------------------------- combine the KV splits
__global__ __launch_bounds__(256) void attn_combine(const float* __restrict__ pacc,
    const float* __restrict__ pml, bf16* __restrict__ out) {
  const int q = blockIdx.x;
  const int tid = threadIdx.x;
  const float2* mlp = (const float2*)pml;
  #pragma unroll
  for (int i = 0; i < 3; ++i) {
    const int c = tid + i * 256;
    const int h = c >> 6;
    const float2 ml0 = mlp[(size_t)h * T_SEQ + q];
    const float2 ml1 = mlp[((size_t)NHEAD + h) * T_SEQ + q];
    const float M = fmaxf(ml0.x, ml1.x);
    const float w0 = expx(ml0.x - M), w1 = expx(ml1.x - M);
    const float inv = 1.0f / (ml0.y * w0 + ml1.y * w1);
    const float a0 = pacc[(size_t)q * C_EMBD + c];
    const float a1 = pacc[(size_t)T_SEQ * C_EMBD + (size_t)q * C_EMBD + c];
    out[(size_t)q * C_EMBD + c] = __float2bfloat16((a0 * w0 + a1 * w1) * inv);
  }
}

// ---------------------------------------------------------------- launch
extern "C" void kernel_launch(void* const* d_in, const int* in_sizes, int n_in,
                              void* d_out, int out_size, void* d_ws, size_t ws_size,
                              hipStream_t stream) {
  const float* x      = (const float*)d_in[0];
  const float* ln1_g  = (const float*)d_in[1];
  const float* ln1_b  = (const float*)d_in[2];
  const float* w_attn = (const float*)d_in[3];
  const float* b_attn = (const float*)d_in[4];
  const float* w_ao   = (const float*)d_in[5];
  const float* b_ao   = (const float*)d_in[6];
  const float* ln2_g  = (const float*)d_in[7];
  const float* ln2_b  = (const float*)d_in[8];
  const float* w_fc   = (const float*)d_in[9];
  const float* b_fc   = (const float*)d_in[10];
  const float* w_proj = (const float*)d_in[11];
  const float* b_proj = (const float*)d_in[12];

  char* ws = (char*)d_ws;
  size_t off = 0;
  auto alloc = [&](size_t nbytes) {
    char* p = ws + off;
    off += (nbytes + 255) & ~(size_t)255;
    return p;
  };
  bf16* wT_attn = (bf16*)alloc((size_t)C3 * C_EMBD * 2);        // [2304][768]
  bf16* wT_ao   = (bf16*)alloc((size_t)C_EMBD * C_EMBD * 2);    // [768][768]
  bf16* wT_fc   = (bf16*)alloc((size_t)4 * C_EMBD * C_EMBD * 2);// [3072][768]
  bf16* wT_proj = (bf16*)alloc((size_t)C_EMBD * 4 * C_EMBD * 2);// [768][3072]
  bf16* h       = (bf16*)alloc((size_t)T_SEQ * C_EMBD * 2);     // ln out (reused)
  bf16* qkv     = (bf16*)alloc((size_t)T_SEQ * C3 * 2);
  bf16* y       = (bf16*)alloc((size_t)T_SEQ * C_EMBD * 2);     // attn out
  float* x1     = (float*)alloc((size_t)T_SEQ * C_EMBD * 4);    // residual 1
  bf16* hf      = (bf16*)alloc((size_t)T_SEQ * 4 * C_EMBD * 2); // gelu out
  float* pml    = (float*)alloc((size_t)KVSPLIT * NHEAD * T_SEQ * 2 * 4); // (m,l) partials
  // Scratch lifetime plan (all aliases of buffers dead at time of use):
  //  - attn partials pacc -> hf (consumed by attn_combine, before ao GEMM)
  //  - ao split-K partials pa0/pa1 -> hf, hf+T*C floats (consumed by ln2_fused,
  //    then hf is rewritten by the fc GEMM)
  //  - proj split-K partials pp0 -> d_out, pp1 -> qkv (consumed by splitk_combine)
  float* pacc   = (float*)hf;
  float* pa0    = (float*)hf;
  float* pa1    = (float*)hf + (size_t)T_SEQ * C_EMBD;
  float* pp0    = (float*)d_out;
  float* pp1    = (float*)qkv;
  (void)ws_size; (void)in_sizes; (void)n_in; (void)out_size;

  // fused weight transposes + ln1 — one launch (6912 transpose tiles + 4096 LN rows)
  transpose4_ln_kernel<<<6912 + T_SEQ, dim3(32, 8), 0, stream>>>(
      w_attn, wT_attn, w_ao, wT_ao, w_fc, wT_fc, w_proj, wT_proj,
      x, ln1_g, ln1_b, h);

  // qkv = h @ w_attn + b_attn  (bf16 out)
  gemm_bt<0><<<dim3(C3 / 128, T_SEQ / 128), 256, 0, stream>>>(h, wT_attn, b_attn, nullptr, qkv,
                                                              nullptr, T_SEQ, C3, C_EMBD, C_EMBD);
  // attention (kv-split 2) + combine
  attn_kernel<<<dim3(T_SEQ / 128, NHEAD, KVSPLIT), 256, 0, stream>>>(qkv, pacc, pml);
  attn_combine<<<T_SEQ, 256, 0, stream>>>(pacc, pml, y);
  // ao: split-K=2 deterministic partials (pa0/pa1 -> hf scratch)
  gemm_bt<4><<<dim3(C_EMBD / 128, T_SEQ / 128, 2), 256, 0, stream>>>(y, wT_ao, nullptr, nullptr,
                                                                     pa0, pa1, T_SEQ, C_EMBD,
                                                                     C_EMBD / 2, C_EMBD);
  // ln2 fused with ao combine: x1 = pa0+pa1+x+b_ao ; h = LN(x1)
  ln2_fused_kernel<<<T_SEQ, 256, 0, stream>>>(pa0, pa1, x, b_ao, ln2_g, ln2_b, h, x1);
  // hf = gelu(h @ w_fc + b_fc)  (bf16 out)
  gemm_bt<2><<<dim3(4 * C_EMBD / 128, T_SEQ / 128), 256, 0, stream>>>(h, wT_fc, b_fc, nullptr, hf,
                                                                      nullptr, T_SEQ, 4 * C_EMBD,
                                                                      C_EMBD, C_EMBD);
  // proj: split-K=2 deterministic partials (z0 -> d_out scratch, z1 -> qkv scratch)
  gemm_bt<4><<<dim3(C_EMBD / 128, T_SEQ / 128, 2), 256, 0, stream>>>(hf, wT_proj, nullptr, nullptr,
                                                                     pp0, pp1, T_SEQ, C_EMBD,
                                                                     2 * C_EMBD, 4 * C_EMBD);
  // out = p0 + p1 + x1 + b_proj
  splitk_combine<<<T_SEQ, 256, 0, stream>>>(pp0, pp1, x1, b_proj, (float*)d_out);
}

// Round 12
// 220.557 us; speedup vs baseline: 1.0559x; 1.0559x over previous
//
#include <hip/hip_runtime.h>
#include <hip/hip_bf16.h>
#include <cstdint>
#include <cstddef>

typedef __hip_bfloat16 bf16;
typedef __attribute__((ext_vector_type(8))) short short8;
typedef __attribute__((ext_vector_type(4))) float f32x4;
typedef __attribute__((ext_vector_type(16))) float f32x16;

#define C_EMBD 768
#define C3     2304
#define T_SEQ  4096
#define NHEAD  12
#define KVSPLIT 2

// ---------------------------------------------------------------- helpers
__device__ __forceinline__ void load16(const void* g, void* lds) {
  __builtin_amdgcn_global_load_lds(
      (const __attribute__((address_space(1))) uint32_t*)g,
      (__attribute__((address_space(3))) uint32_t*)lds, 16, 0, 0);
}

__device__ __forceinline__ short f2bf_bits(float x) {
  union { bf16 h; short s; } u; u.h = __float2bfloat16(x); return u.s;
}

__device__ __forceinline__ float bfbits2f(short s) {
  union { uint32_t u; float f; } u; u.u = ((uint32_t)(unsigned short)s) << 16; return u.f;
}

__device__ __forceinline__ float max3f(float a, float b, float c) {
  float d;
  asm("v_max3_f32 %0, %1, %2, %3" : "=v"(d) : "v"(a), "v"(b), "v"(c));
  return d;
}

// exp in log2-domain when native exp2 builtin is available (folds log2e into Q scale)
#if __has_builtin(__builtin_amdgcn_exp2f)
#define QK_SCALE (0.125f * 1.44269504088896340736f)
__device__ __forceinline__ float expx(float x) { return __builtin_amdgcn_exp2f(x); }
#else
#define QK_SCALE 0.125f
__device__ __forceinline__ float expx(float x) { return __expf(x); }
#endif

// ---------------------------------------------------------------- LN2 fused with ao split-K combine:
// xv = pa0 + pa1 + x + b_ao ; x1 = xv ; out = bf16(LN(xv))
__global__ __launch_bounds__(256) void ln2_fused_kernel(
    const float* __restrict__ pa0, const float* __restrict__ pa1,
    const float* __restrict__ x, const float* __restrict__ b_ao,
    const float* __restrict__ g, const float* __restrict__ b,
    bf16* __restrict__ out, float* __restrict__ x1) {
  const int row = blockIdx.x;
  const int tid = threadIdx.x;
  const int lane = tid & 63, wave = tid >> 6;
  float v[3];
  #pragma unroll
  for (int i = 0; i < 3; ++i) {
    const int c = tid + i * 256;
    const size_t idx = (size_t)row * C_EMBD + c;
    v[i] = pa0[idx] + pa1[idx] + x[idx] + b_ao[c];
    x1[idx] = v[i];
  }
  float s = v[0] + v[1] + v[2];
  #pragma unroll
  for (int o = 1; o < 64; o <<= 1) s += __shfl_xor(s, o, 64);
  __shared__ float red[4];
  if (lane == 0) red[wave] = s;
  __syncthreads();
  const float mu = (red[0] + red[1] + red[2] + red[3]) * (1.0f / C_EMBD);
  float d0 = v[0] - mu, d1 = v[1] - mu, d2 = v[2] - mu;
  float q = d0 * d0 + d1 * d1 + d2 * d2;
  #pragma unroll
  for (int o = 1; o < 64; o <<= 1) q += __shfl_xor(q, o, 64);
  __syncthreads();
  if (lane == 0) red[wave] = q;
  __syncthreads();
  const float var = (red[0] + red[1] + red[2] + red[3]) * (1.0f / C_EMBD);
  const float rs = rsqrtf(var + 1e-5f);
  #pragma unroll
  for (int i = 0; i < 3; ++i) {
    int c = tid + i * 256;
    out[(size_t)row * C_EMBD + c] = __float2bfloat16((v[i] - mu) * rs * g[c] + b[c]);
  }
}

// ---------------------------------------------------------------- fused 4x transpose + ln1
// blocks 0..6911: weight transposes fp32 [R][C] -> bf16 [C][R]
// blocks 6912..11007: ln1 rows (4096) — h = bf16(LN(x))
__global__ __launch_bounds__(256) void transpose4_ln_kernel(
    const float* __restrict__ wA, bf16* __restrict__ oA,
    const float* __restrict__ wB, bf16* __restrict__ oB,
    const float* __restrict__ wC, bf16* __restrict__ oC,
    const float* __restrict__ wD, bf16* __restrict__ oD,
    const float* __restrict__ x, const float* __restrict__ lg,
    const float* __restrict__ lb, bf16* __restrict__ oh) {
  __shared__ float tile[32][33];
  __shared__ float red[4];
  int b = blockIdx.x;
  if (b >= 6912) {
    // ---- LN1 path
    const int row = b - 6912;
    const int tid = threadIdx.y * 32 + threadIdx.x;
    const int lane = tid & 63, wave = tid >> 6;
    const float* xr = x + (size_t)row * C_EMBD;
    float v[3];
    #pragma unroll
    for (int i = 0; i < 3; ++i) v[i] = xr[tid + i * 256];
    float s = v[0] + v[1] + v[2];
    #pragma unroll
    for (int o = 1; o < 64; o <<= 1) s += __shfl_xor(s, o, 64);
    if (lane == 0) red[wave] = s;
    __syncthreads();
    const float mu = (red[0] + red[1] + red[2] + red[3]) * (1.0f / C_EMBD);
    float d0 = v[0] - mu, d1 = v[1] - mu, d2 = v[2] - mu;
    float q = d0 * d0 + d1 * d1 + d2 * d2;
    #pragma unroll
    for (int o = 1; o < 64; o <<= 1) q += __shfl_xor(q, o, 64);
    __syncthreads();
    if (lane == 0) red[wave] = q;
    __syncthreads();
    const float var = (red[0] + red[1] + red[2] + red[3]) * (1.0f / C_EMBD);
    const float rs = rsqrtf(var + 1e-5f);
    #pragma unroll
    for (int i = 0; i < 3; ++i) {
      int c = tid + i * 256;
      oh[(size_t)row * C_EMBD + c] = __float2bfloat16((v[i] - mu) * rs * lg[c] + lb[c]);
    }
    return;
  }
  // ---- transpose path
  const float* in; bf16* out; int R, C;
  if (b < 1728)      { in = wA; out = oA; R = 768;  C = 2304; }
  else if (b < 2304) { b -= 1728; in = wB; out = oB; R = 768;  C = 768;  }
  else if (b < 4608) { b -= 2304; in = wC; out = oC; R = 768;  C = 3072; }
  else               { b -= 4608; in = wD; out = oD; R = 3072; C = 768;  }
  const int ntx = C / 32;
  const int bx = (b % ntx) * 32;  // col in 'in'
  const int by = (b / ntx) * 32;  // row in 'in'
  const int tx = threadIdx.x, ty = threadIdx.y;
  #pragma unroll
  for (int i = 0; i < 32; i += 8)
    tile[ty + i][tx] = in[(size_t)(by + ty + i) * C + bx + tx];
  __syncthreads();
  #pragma unroll
  for (int i = 0; i < 32; i += 8)
    out[(size_t)(bx + ty + i) * R + by + tx] = __float2bfloat16(tile[tx][ty + i]);
}

// ---------------------------------------------------------------- GEMM: A[M][K] bf16 x BT[N][K] bf16
// Round-9 structure (16x16x32 MFMA, 2-phase dbuf, launch_bounds(256,3)) + T1 XCD-aware
// block swizzle: flat block ids are chunked so each XCD gets a contiguous range
// (consecutive ids share the A-row panel -> A fetched once per XCD chunk instead of
// once per XCD per panel; B panels stay L2-resident). Bijective: all grids have
// gridDim.x*gridDim.y % 8 == 0 (576 / 768 / 192-per-z).
// EPI 0: out = bf16(acc + bias)
// EPI 2: out = bf16(gelu(acc + bias))
// EPI 4: split-K over blockIdx.z (deterministic): z==0 -> outp, z==1 -> outp2, raw f32 acc
template <int EPI>
__global__ __launch_bounds__(256, 3) void gemm_bt(
    const bf16* __restrict__ A, const bf16* __restrict__ BT,
    const float* __restrict__ bias, const float* __restrict__ res,
    void* __restrict__ outp, float* __restrict__ outp2, int M, int N, int Ks, int Kst) {
  __shared__ __align__(16) short sA[2][128 * 32];
  __shared__ __align__(16) short sB[2][128 * 32];
  const int tid = threadIdx.x;
  const int wave = tid >> 6, lane = tid & 63;
  const int qr = lane >> 4, qm = lane & 15;
  const int wr = wave >> 1, wc = wave & 1;
  // XCD-aware chunked swizzle of the (x,y) block id (z untouched)
  const int gx = gridDim.x;
  int flat = blockIdx.y * gx + blockIdx.x;
  const int cpx = (gx * gridDim.y) >> 3;  // nwg/8, exact for all our grids
  flat = (flat & 7) * cpx + (flat >> 3);
  const int tM = (flat / gx) * 128, tN = (flat % gx) * 128;
  const int z = (EPI == 4) ? blockIdx.z : 0;

  f32x4 acc[4][4] = {};

  const int srow = tid >> 2;
  const int scol = (tid & 3) * 8;
  const bf16* gA = A + (size_t)z * Ks + (size_t)(tM + srow) * Kst + scol;
  const bf16* gB = BT + (size_t)z * Ks + (size_t)(tN + srow) * Kst + scol;
  const int woff = wave * 1024;
  const size_t rowskip = (size_t)64 * Kst;

  const int nk = Ks >> 5;
  // prologue: stage k-step 0 into buffer 0
  {
    char* la = (char*)sA[0] + woff;
    char* lb = (char*)sB[0] + woff;
    load16(gA, la);
    load16(gA + rowskip, la + 4096);
    load16(gB, lb);
    load16(gB + rowskip, lb + 4096);
    gA += 32; gB += 32;
  }
  __syncthreads();  // prologue loads drained

  int cur = 0;
  for (int k0 = 0; k0 < nk; ++k0) {
    // issue stage of k-step k0+1 into the other buffer (overlaps compute below)
    if (k0 + 1 < nk) {
      char* la = (char*)sA[cur ^ 1] + woff;
      char* lb = (char*)sB[cur ^ 1] + woff;
      load16(gA, la);
      load16(gA + rowskip, la + 4096);
      load16(gB, lb);
      load16(gB + rowskip, lb + 4096);
      gA += 32; gB += 32;
    }
    // compute from buffer cur
    const short* bufA = sA[cur];
    const short* bufB = sB[cur];
    short8 a[4], bb[4];
    #pragma unroll
    for (int i = 0; i < 4; ++i) {
      a[i]  = *(const short8*)&bufA[(wr * 64 + i * 16 + qm) * 32 + qr * 8];
      bb[i] = *(const short8*)&bufB[(wc * 64 + i * 16 + qm) * 32 + qr * 8];
    }
    #pragma unroll
    for (int mi = 0; mi < 4; ++mi)
      #pragma unroll
      for (int ni = 0; ni < 4; ++ni)
        acc[mi][ni] = __builtin_amdgcn_mfma_f32_16x16x32_bf16(a[mi], bb[ni], acc[mi][ni], 0, 0, 0);
    __syncthreads();  // all waves done reading cur; next-buffer stage drained
    cur ^= 1;
  }

  bf16* outh = (bf16*)outp;
  float* po = (EPI == 4) ? ((z == 0) ? (float*)outp : outp2) : nullptr;
  #pragma unroll
  for (int mi = 0; mi < 4; ++mi) {
    #pragma unroll
    for (int ni = 0; ni < 4; ++ni) {
      const int col = tN + wc * 64 + ni * 16 + qm;
      const float bv = (EPI == 4) ? 0.f : bias[col];
      #pragma unroll
      for (int r = 0; r < 4; ++r) {
        const int row = tM + wr * 64 + mi * 16 + qr * 4 + r;
        const size_t idx = (size_t)row * N + col;
        float v = acc[mi][ni][r] + bv;
        if constexpr (EPI == 4) {
          po[idx] = v;
        } else if constexpr (EPI == 2) {
          v = 0.5f * v * (1.0f + erff(v * 0.70710678118654752f));
          outh[idx] = __float2bfloat16(v);
        } else {
          outh[idx] = __float2bfloat16(v);
        }
      }
    }
  }
  (void)res;
}

// ---------------------------------------------------------------- split-K combine: out = p0+p1+res+bias
// (p0 may alias out: each thread reads its element before writing it)
__global__ __launch_bounds__(256) void splitk_combine(const float* p0,
    const float* __restrict__ p1, const float* __restrict__ res,
    const float* __restrict__ bias, float* out) {
  const int row = blockIdx.x;
  const int tid = threadIdx.x;
  #pragma unroll
  for (int i = 0; i < 3; ++i) {
    const int c = tid + i * 256;
    const size_t idx = (size_t)row * C_EMBD + c;
    out[idx] = p0[idx] + p1[idx] + res[idx] + bias[c];
  }
}

// ---------------------------------------------------------------- flash attention fwd (no mask), v6 (round-4/6 best)
// Swapped QK^T 32x32x16, in-register softmax, KVSPLIT=2, delayed-PV pipeline.
// Grid: (T/128, NHEAD, KVSPLIT), block 256 (4 waves x 32 q-rows).
__global__ __launch_bounds__(256, 2) void attn_kernel(const bf16* __restrict__ qkv,
                                                      float* __restrict__ pacc,
                                                      float* __restrict__ pml) {
  __shared__ __align__(16) char sKb[2 * 8192];
  __shared__ __align__(16) char sVb[2 * 8192];
  __shared__ float sRed[4 * 32];

  const int tid = threadIdx.x;
  const int wave = tid >> 6, lane = tid & 63;
  const int qi = lane & 31;
  const int hi = lane >> 5;
  const int hi16 = hi * 16;
  const int head = blockIdx.y;
  const int z = blockIdx.z;
  const int qw = blockIdx.x * 128 + wave * 32;

  short8 qf[4];
  {
    const bf16* qrow = qkv + (size_t)(qw + qi) * C3 + head * 64;
    #pragma unroll
    for (int kd = 0; kd < 4; ++kd) {
      short8 v = *(const short8*)(qrow + kd * 16 + hi * 8);
      #pragma unroll
      for (int i = 0; i < 8; ++i) v[i] = f2bf_bits(bfbits2f(v[i]) * QK_SCALE);
      qf[kd] = v;
    }
  }

  f32x16 acc0 = {}, acc1 = {};
  float m = -3.0e38f, l = 0.f;
  short8 pfrag[4];

  const int nt = (T_SEQ / 64) / KVSPLIT;
  const size_t tilestep = (size_t)64 * C3;
  const size_t zoff = (size_t)z * nt * tilestep;
  const int ksrow = tid >> 3;
  const int kswz = ((tid & 7) ^ (ksrow & 7)) * 8;
  const bf16* gk_base = qkv + zoff + (size_t)ksrow * C3 + C_EMBD + head * 64 + kswz;
  const int vp = tid & 31;
  const int vd0 = (tid >> 5) * 8;
  const bf16* gv_base = qkv + zoff + (size_t)(2 * vp) * C3 + 2 * C_EMBD + head * 64 + vd0;

  const int krow0 = qi * 128;
  const int krow_swz = (qi & 7) << 4;
  const int d1 = 32 + qi;
  const int vs0 = ((qi & 7) ^ ((qi >> 3) & 7)) << 4;
  const int vs1 = ((d1 & 7) ^ ((d1 >> 3) & 7)) << 4;

  short8 v0 = *(const short8*)gv_base;
  short8 v1 = *(const short8*)(gv_base + C3);
  load16(gk_base, sKb + wave * 1024);
  load16(gk_base + (size_t)32 * C3, sKb + wave * 1024 + 4096);

  for (int t = 0; t < nt; ++t) {
    const int cur = t & 1;
    char* bK = sKb + cur * 8192;
    char* bV = sVb + cur * 8192;

    __syncthreads();

    #pragma unroll
    for (int j = 0; j < 8; ++j) {
      const int d = vd0 + j;
      const int vs = ((d & 7) ^ ((d >> 3) & 7)) << 4;
      const uint32_t packed = (uint32_t)(unsigned short)v0[j] |
                              ((uint32_t)(unsigned short)v1[j] << 16);
      *(uint32_t*)(bV + d * 128 + ((vp * 4) ^ vs)) = packed;
    }

    if (t + 1 < nt) {
      const bf16* gv = gv_base + (size_t)(t + 1) * tilestep;
      v0 = *(const short8*)gv;
      v1 = *(const short8*)(gv + C3);
      const bf16* gk = gk_base + (size_t)(t + 1) * tilestep;
      char* bKn = sKb + (cur ^ 1) * 8192;
      load16(gk, bKn + wave * 1024);
      load16(gk + (size_t)32 * C3, bKn + wave * 1024 + 4096);
    }

    f32x16 s0 = {}, s1 = {};
    __builtin_amdgcn_s_setprio(1);
    #pragma unroll
    for (int kd = 0; kd < 4; ++kd) {
      const int off = (kd * 32 + hi16) ^ krow_swz;
      short8 ka0 = *(const short8*)(bK + krow0 + off);
      short8 ka1 = *(const short8*)(bK + 4096 + krow0 + off);
      s0 = __builtin_amdgcn_mfma_f32_32x32x16_bf16(ka0, qf[kd], s0, 0, 0, 0);
      s1 = __builtin_amdgcn_mfma_f32_32x32x16_bf16(ka1, qf[kd], s1, 0, 0, 0);
    }

    if (t > 0) {
      char* bVp = sVb + (cur ^ 1) * 8192;
      #pragma unroll
      for (int kk = 0; kk < 4; ++kk) {
        const int voff = (kk * 32 + hi16);
        short8 vb0 = *(const short8*)(bVp + qi * 128 + (voff ^ vs0));
        short8 vb1 = *(const short8*)(bVp + d1 * 128 + (voff ^ vs1));
        acc0 = __builtin_amdgcn_mfma_f32_32x32x16_bf16(pfrag[kk], vb0, acc0, 0, 0, 0);
        acc1 = __builtin_amdgcn_mfma_f32_32x32x16_bf16(pfrag[kk], vb1, acc1, 0, 0, 0);
      }
    }
    __builtin_amdgcn_s_setprio(0);

    float t8[8];
    #pragma unroll
    for (int i = 0; i < 8; ++i) t8[i] = max3f(s0[i], s0[i + 8], s1[i]);
    float t4[4];
    #pragma unroll
    for (int i = 0; i < 4; ++i) t4[i] = max3f(t8[2 * i], t8[2 * i + 1], s1[8 + i]);
    float t2[2];
    #pragma unroll
    for (int i = 0; i < 2; ++i) t2[i] = max3f(t4[2 * i], t4[2 * i + 1], s1[12 + i]);
    const float t1 = max3f(t2[0], t2[1], s1[14]);
    const float tmx = fmaxf(t1, s1[15]);
    float pmax;
    {
      float a0 = tmx, a1 = tmx;
      asm("v_permlane32_swap_b32 %0, %1" : "+v"(a0), "+v"(a1));
      pmax = fmaxf(a0, a1);
    }

    if (__any(pmax - m > 8.0f)) {
      const float mn = fmaxf(m, pmax);
      const float sc = expx(m - mn);
      l *= sc;
      if (lane < 32) sRed[wave * 32 + qi] = sc;
      #pragma unroll
      for (int r = 0; r < 16; ++r) {
        const float sv = sRed[wave * 32 + ((r & 3) + 8 * (r >> 2) + hi * 4)];
        acc0[r] *= sv; acc1[r] *= sv;
      }
      m = mn;
    }

    float red[16];
    #pragma unroll
    for (int r = 0; r < 16; ++r) { s0[r] = expx(s0[r] - m); s1[r] = expx(s1[r] - m); }
    #pragma unroll
    for (int r = 0; r < 16; ++r) red[r] = s0[r] + s1[r];
    #pragma unroll
    for (int w = 8; w >= 1; w >>= 1)
      #pragma unroll
      for (int r = 0; r < w; ++r) red[r] += red[r + w];
    {
      float a0 = red[0], a1 = red[0];
      asm("v_permlane32_swap_b32 %0, %1" : "+v"(a0), "+v"(a1));
      l += a0 + a1;
    }

    #pragma unroll
    for (int b = 0; b < 2; ++b) {
      const f32x16 sb = b ? s1 : s0;
      uint32_t pk[8];
      #pragma unroll
      for (int g = 0; g < 4; ++g) {
        asm("v_cvt_pk_bf16_f32 %0, %1, %2" : "=v"(pk[2 * g])     : "v"(sb[4 * g + 0]), "v"(sb[4 * g + 1]));
        asm("v_cvt_pk_bf16_f32 %0, %1, %2" : "=v"(pk[2 * g + 1]) : "v"(sb[4 * g + 2]), "v"(sb[4 * g + 3]));
      }
      #pragma unroll
      for (int kbl = 0; kbl < 2; ++kbl) {
        uint32_t w0 = pk[4 * kbl + 0], w2 = pk[4 * kbl + 2];
        asm("v_permlane32_swap_b32 %0, %1" : "+v"(w0), "+v"(w2));
        uint32_t w1 = pk[4 * kbl + 1], w3 = pk[4 * kbl + 3];
        asm("v_permlane32_swap_b32 %0, %1" : "+v"(w1), "+v"(w3));
        union { uint32_t u[4]; short8 v; } pu;
        pu.u[0] = w0; pu.u[1] = w1; pu.u[2] = w2; pu.u[3] = w3;
        pfrag[b * 2 + kbl] = pu.v;
      }
    }
  }

  __syncthreads();
  {
    char* bVl = sVb + ((nt - 1) & 1) * 8192;
    __builtin_amdgcn_s_setprio(1);
    #pragma unroll
    for (int kk = 0; kk < 4; ++kk) {
      const int voff = (kk * 32 + hi16);
      short8 vb0 = *(const short8*)(bVl + qi * 128 + (voff ^ vs0));
      short8 vb1 = *(const short8*)(bVl + d1 * 128 + (voff ^ vs1));
      acc0 = __builtin_amdgcn_mfma_f32_32x32x16_bf16(pfrag[kk], vb0, acc0, 0, 0, 0);
      acc1 = __builtin_amdgcn_mfma_f32_32x32x16_bf16(pfrag[kk], vb1, acc1, 0, 0, 0);
    }
    __builtin_amdgcn_s_setprio(0);
  }

  float* pa = pacc + ((size_t)z * T_SEQ + qw) * C_EMBD + head * 64;
  #pragma unroll
  for (int r = 0; r < 16; ++r) {
    const int q = (r & 3) + 8 * (r >> 2) + hi * 4;
    pa[(size_t)q * C_EMBD + qi]      = acc0[r];
    pa[(size_t)q * C_EMBD + 32 + qi] = acc1[r];
  }
  if (lane < 32) {
    float2* mlp = (float2*)pml;
    mlp[((size_t)z * NHEAD + head) * T_SEQ + qw + qi] = make_float2(m, l);
  }
}

// ---------------------------------------------------------------- combine the KV splits
__global__ __launch_bounds__(256) void attn_combine(const float* __restrict__ pacc,
    const float* __restrict__ pml, bf16* __restrict__ out) {
  const int q = blockIdx.x;
  const int tid = threadIdx.x;
  const float2* mlp = (const float2*)pml;
  #pragma unroll
  for (int i = 0; i < 3; ++i) {
    const int c = tid + i * 256;
    const int h = c >> 6;
    const float2 ml0 = mlp[(size_t)h * T_SEQ + q];
    const float2 ml1 = mlp[((size_t)NHEAD + h) * T_SEQ + q];
    const float M = fmaxf(ml0.x, ml1.x);
    const float w0 = expx(ml0.x - M), w1 = expx(ml1.x - M);
    const float inv = 1.0f / (ml0.y * w0 + ml1.y * w1);
    const float a0 = pacc[(size_t)q * C_EMBD + c];
    const float a1 = pacc[(size_t)T_SEQ * C_EMBD + (size_t)q * C_EMBD + c];
    out[(size_t)q * C_EMBD + c] = __float2bfloat16((a0 * w0 + a1 * w1) * inv);
  }
}

// ---------------------------------------------------------------- launch
extern "C" void kernel_launch(void* const* d_in, const int* in_sizes, int n_in,
                              void* d_out, int out_size, void* d_ws, size_t ws_size,
                              hipStream_t stream) {
  const float* x      = (const float*)d_in[0];
  const float* ln1_g  = (const float*)d_in[1];
  const float* ln1_b  = (const float*)d_in[2];
  const float* w_attn = (const float*)d_in[3];
  const float* b_attn = (const float*)d_in[4];
  const float* w_ao   = (const float*)d_in[5];
  const float* b_ao   = (const float*)d_in[6];
  const float* ln2_g  = (const float*)d_in[7];
  const float* ln2_b  = (const float*)d_in[8];
  const float* w_fc   = (const float*)d_in[9];
  const float* b_fc   = (const float*)d_in[10];
  const float* w_proj = (const float*)d_in[11];
  const float* b_proj = (const float*)d_in[12];

  char* ws = (char*)d_ws;
  size_t off = 0;
  auto alloc = [&](size_t nbytes) {
    char* p = ws + off;
    off += (nbytes + 255) & ~(size_t)255;
    return p;
  };
  bf16* wT_attn = (bf16*)alloc((size_t)C3 * C_EMBD * 2);        // [2304][768]
  bf16* wT_ao   = (bf16*)alloc((size_t)C_EMBD * C_EMBD * 2);    // [768][768]
  bf16* wT_fc   = (bf16*)alloc((size_t)4 * C_EMBD * C_EMBD * 2);// [3072][768]
  bf16* wT_proj = (bf16*)alloc((size_t)C_EMBD * 4 * C_EMBD * 2);// [768][3072]
  bf16* h       = (bf16*)alloc((size_t)T_SEQ * C_EMBD * 2);     // ln out (reused)
  bf16* qkv     = (bf16*)alloc((size_t)T_SEQ * C3 * 2);
  bf16* y       = (bf16*)alloc((size_t)T_SEQ * C_EMBD * 2);     // attn out
  float* x1     = (float*)alloc((size_t)T_SEQ * C_EMBD * 4);    // residual 1
  bf16* hf      = (bf16*)alloc((size_t)T_SEQ * 4 * C_EMBD * 2); // gelu out
  float* pml    = (float*)alloc((size_t)KVSPLIT * NHEAD * T_SEQ * 2 * 4); // (m,l) partials
  // Scratch lifetime plan (all aliases of buffers dead at time of use):
  //  - attn partials pacc -> hf (consumed by attn_combine, before ao GEMM)
  //  - ao split-K partials pa0/pa1 -> hf, hf+T*C floats (consumed by ln2_fused,
  //    then hf is rewritten by the fc GEMM)
  //  - proj split-K partials pp0 -> d_out, pp1 -> qkv (consumed by splitk_combine)
  float* pacc   = (float*)hf;
  float* pa0    = (float*)hf;
  float* pa1    = (float*)hf + (size_t)T_SEQ * C_EMBD;
  float* pp0    = (float*)d_out;
  float* pp1    = (float*)qkv;
  (void)ws_size; (void)in_sizes; (void)n_in; (void)out_size;

  // fused weight transposes + ln1 — one launch (6912 transpose tiles + 4096 LN rows)
  transpose4_ln_kernel<<<6912 + T_SEQ, dim3(32, 8), 0, stream>>>(
      w_attn, wT_attn, w_ao, wT_ao, w_fc, wT_fc, w_proj, wT_proj,
      x, ln1_g, ln1_b, h);

  // qkv = h @ w_attn + b_attn  (bf16 out)
  gemm_bt<0><<<dim3(C3 / 128, T_SEQ / 128), 256, 0, stream>>>(h, wT_attn, b_attn, nullptr, qkv,
                                                              nullptr, T_SEQ, C3, C_EMBD, C_EMBD);
  // attention (kv-split 2) + combine
  attn_kernel<<<dim3(T_SEQ / 128, NHEAD, KVSPLIT), 256, 0, stream>>>(qkv, pacc, pml);
  attn_combine<<<T_SEQ, 256, 0, stream>>>(pacc, pml, y);
  // ao: split-K=2 deterministic partials (pa0/pa1 -> hf scratch)
  gemm_bt<4><<<dim3(C_EMBD / 128, T_SEQ / 128, 2), 256, 0, stream>>>(y, wT_ao, nullptr, nullptr,
                                                                     pa0, pa1, T_SEQ, C_EMBD,
                                                                     C_EMBD / 2, C_EMBD);
  // ln2 fused with ao combine: x1 = pa0+pa1+x+b_ao ; h = LN(x1)
  ln2_fused_kernel<<<T_SEQ, 256, 0, stream>>>(pa0, pa1, x, b_ao, ln2_g, ln2_b, h, x1);
  // hf = gelu(h @ w_fc + b_fc)  (bf16 out)
  gemm_bt<2><<<dim3(4 * C_EMBD / 128, T_SEQ / 128), 256, 0, stream>>>(h, wT_fc, b_fc, nullptr, hf,
                                                                      nullptr, T_SEQ, 4 * C_EMBD,
                                                                      C_EMBD, C_EMBD);
  // proj: split-K=2 deterministic partials (z0 -> d_out scratch, z1 -> qkv scratch)
  gemm_bt<4><<<dim3(C_EMBD / 128, T_SEQ / 128, 2), 256, 0, stream>>>(hf, wT_proj, nullptr, nullptr,
                                                                     pp0, pp1, T_SEQ, C_EMBD,
                                                                     2 * C_EMBD, 4 * C_EMBD);
  // out = p0 + p1 + x1 + b_proj
  splitk_combine<<<T_SEQ, 256, 0, stream>>>(pp0, pp1, x1, b_proj, (float*)d_out);
}

// Round 13
// 216.843 us; speedup vs baseline: 1.0740x; 1.0171x over previous
//
#include <hip/hip_runtime.h>
#include <hip/hip_bf16.h>
#include <cstdint>
#include <cstddef>

typedef __hip_bfloat16 bf16;
typedef __attribute__((ext_vector_type(8))) short short8;
typedef __attribute__((ext_vector_type(4))) float f32x4;
typedef __attribute__((ext_vector_type(16))) float f32x16;

#define C_EMBD 768
#define C3     2304
#define T_SEQ  4096
#define NHEAD  12
#define KVSPLIT 2

// ---------------------------------------------------------------- helpers
__device__ __forceinline__ void load16(const void* g, void* lds) {
  __builtin_amdgcn_global_load_lds(
      (const __attribute__((address_space(1))) uint32_t*)g,
      (__attribute__((address_space(3))) uint32_t*)lds, 16, 0, 0);
}

__device__ __forceinline__ short f2bf_bits(float x) {
  union { bf16 h; short s; } u; u.h = __float2bfloat16(x); return u.s;
}

__device__ __forceinline__ float bfbits2f(short s) {
  union { uint32_t u; float f; } u; u.u = ((uint32_t)(unsigned short)s) << 16; return u.f;
}

__device__ __forceinline__ float max3f(float a, float b, float c) {
  float d;
  asm("v_max3_f32 %0, %1, %2, %3" : "=v"(d) : "v"(a), "v"(b), "v"(c));
  return d;
}

// exp in log2-domain when native exp2 builtin is available (folds log2e into Q scale)
#if __has_builtin(__builtin_amdgcn_exp2f)
#define QK_SCALE (0.125f * 1.44269504088896340736f)
__device__ __forceinline__ float expx(float x) { return __builtin_amdgcn_exp2f(x); }
#else
#define QK_SCALE 0.125f
__device__ __forceinline__ float expx(float x) { return __expf(x); }
#endif

// ---------------------------------------------------------------- LN2 fused with ao split-K combine:
// xv = pa0 + pa1 + x + b_ao ; x1 = xv ; out = bf16(LN(xv))
__global__ __launch_bounds__(256) void ln2_fused_kernel(
    const float* __restrict__ pa0, const float* __restrict__ pa1,
    const float* __restrict__ x, const float* __restrict__ b_ao,
    const float* __restrict__ g, const float* __restrict__ b,
    bf16* __restrict__ out, float* __restrict__ x1) {
  const int row = blockIdx.x;
  const int tid = threadIdx.x;
  const int lane = tid & 63, wave = tid >> 6;
  float v[3];
  #pragma unroll
  for (int i = 0; i < 3; ++i) {
    const int c = tid + i * 256;
    const size_t idx = (size_t)row * C_EMBD + c;
    v[i] = pa0[idx] + pa1[idx] + x[idx] + b_ao[c];
    x1[idx] = v[i];
  }
  float s = v[0] + v[1] + v[2];
  #pragma unroll
  for (int o = 1; o < 64; o <<= 1) s += __shfl_xor(s, o, 64);
  __shared__ float red[4];
  if (lane == 0) red[wave] = s;
  __syncthreads();
  const float mu = (red[0] + red[1] + red[2] + red[3]) * (1.0f / C_EMBD);
  float d0 = v[0] - mu, d1 = v[1] - mu, d2 = v[2] - mu;
  float q = d0 * d0 + d1 * d1 + d2 * d2;
  #pragma unroll
  for (int o = 1; o < 64; o <<= 1) q += __shfl_xor(q, o, 64);
  __syncthreads();
  if (lane == 0) red[wave] = q;
  __syncthreads();
  const float var = (red[0] + red[1] + red[2] + red[3]) * (1.0f / C_EMBD);
  const float rs = rsqrtf(var + 1e-5f);
  #pragma unroll
  for (int i = 0; i < 3; ++i) {
    int c = tid + i * 256;
    out[(size_t)row * C_EMBD + c] = __float2bfloat16((v[i] - mu) * rs * g[c] + b[c]);
  }
}

// ---------------------------------------------------------------- w_attn transpose + ln1
// blocks 0..1727: w_attn 768x2304 fp32 -> bf16 [2304][768]
// blocks 1728..5823: ln1 rows (4096) — h = bf16(LN(x))
__global__ __launch_bounds__(256) void transpose1_ln_kernel(
    const float* __restrict__ wA, bf16* __restrict__ oA,
    const float* __restrict__ x, const float* __restrict__ lg,
    const float* __restrict__ lb, bf16* __restrict__ oh) {
  __shared__ float tile[32][33];
  __shared__ float red[4];
  int b = blockIdx.x;
  const int tid = threadIdx.x;
  if (b >= 1728) {
    // ---- LN1 path
    const int row = b - 1728;
    const int lane = tid & 63, wave = tid >> 6;
    const float* xr = x + (size_t)row * C_EMBD;
    float v[3];
    #pragma unroll
    for (int i = 0; i < 3; ++i) v[i] = xr[tid + i * 256];
    float s = v[0] + v[1] + v[2];
    #pragma unroll
    for (int o = 1; o < 64; o <<= 1) s += __shfl_xor(s, o, 64);
    if (lane == 0) red[wave] = s;
    __syncthreads();
    const float mu = (red[0] + red[1] + red[2] + red[3]) * (1.0f / C_EMBD);
    float d0 = v[0] - mu, d1 = v[1] - mu, d2 = v[2] - mu;
    float q = d0 * d0 + d1 * d1 + d2 * d2;
    #pragma unroll
    for (int o = 1; o < 64; o <<= 1) q += __shfl_xor(q, o, 64);
    __syncthreads();
    if (lane == 0) red[wave] = q;
    __syncthreads();
    const float var = (red[0] + red[1] + red[2] + red[3]) * (1.0f / C_EMBD);
    const float rs = rsqrtf(var + 1e-5f);
    #pragma unroll
    for (int i = 0; i < 3; ++i) {
      int c = tid + i * 256;
      oh[(size_t)row * C_EMBD + c] = __float2bfloat16((v[i] - mu) * rs * lg[c] + lb[c]);
    }
    return;
  }
  // ---- transpose path (w_attn: R=768, C=2304)
  const int ntx = C3 / 32;
  const int bx = (b % ntx) * 32;
  const int by = (b / ntx) * 32;
  const int tx = tid & 31, ty = tid >> 5;
  #pragma unroll
  for (int i = 0; i < 32; i += 8)
    tile[ty + i][tx] = wA[(size_t)(by + ty + i) * C3 + bx + tx];
  __syncthreads();
  #pragma unroll
  for (int i = 0; i < 32; i += 8)
    oA[(size_t)(bx + ty + i) * C_EMBD + by + tx] = __float2bfloat16(tile[tx][ty + i]);
}

// ---------------------------------------------------------------- GEMM: A[M][K] bf16 x BT[N][K] bf16
// Round-9 structure (16x16x32 MFMA, 2-phase dbuf, launch_bounds(256,3)) + T1 XCD-aware
// chunked block swizzle (bijective: all grids have nwg % 8 == 0).
// EPI 0: out = bf16(acc + bias)
// EPI 2: out = bf16(gelu(acc + bias))
// EPI 4: split-K over blockIdx.z (deterministic): z==0 -> outp, z==1 -> outp2, raw f32 acc
template <int EPI>
__global__ __launch_bounds__(256, 3) void gemm_bt(
    const bf16* __restrict__ A, const bf16* __restrict__ BT,
    const float* __restrict__ bias, const float* __restrict__ res,
    void* __restrict__ outp, float* __restrict__ outp2, int M, int N, int Ks, int Kst) {
  __shared__ __align__(16) short sA[2][128 * 32];
  __shared__ __align__(16) short sB[2][128 * 32];
  const int tid = threadIdx.x;
  const int wave = tid >> 6, lane = tid & 63;
  const int qr = lane >> 4, qm = lane & 15;
  const int wr = wave >> 1, wc = wave & 1;
  // XCD-aware chunked swizzle of the (x,y) block id (z untouched)
  const int gx = gridDim.x;
  int flat = blockIdx.y * gx + blockIdx.x;
  const int cpx = (gx * gridDim.y) >> 3;  // nwg/8, exact for all our grids
  flat = (flat & 7) * cpx + (flat >> 3);
  const int tM = (flat / gx) * 128, tN = (flat % gx) * 128;
  const int z = (EPI == 4) ? blockIdx.z : 0;

  f32x4 acc[4][4] = {};

  const int srow = tid >> 2;
  const int scol = (tid & 3) * 8;
  const bf16* gA = A + (size_t)z * Ks + (size_t)(tM + srow) * Kst + scol;
  const bf16* gB = BT + (size_t)z * Ks + (size_t)(tN + srow) * Kst + scol;
  const int woff = wave * 1024;
  const size_t rowskip = (size_t)64 * Kst;

  const int nk = Ks >> 5;
  // prologue: stage k-step 0 into buffer 0
  {
    char* la = (char*)sA[0] + woff;
    char* lb = (char*)sB[0] + woff;
    load16(gA, la);
    load16(gA + rowskip, la + 4096);
    load16(gB, lb);
    load16(gB + rowskip, lb + 4096);
    gA += 32; gB += 32;
  }
  __syncthreads();  // prologue loads drained

  int cur = 0;
  for (int k0 = 0; k0 < nk; ++k0) {
    // issue stage of k-step k0+1 into the other buffer (overlaps compute below)
    if (k0 + 1 < nk) {
      char* la = (char*)sA[cur ^ 1] + woff;
      char* lb = (char*)sB[cur ^ 1] + woff;
      load16(gA, la);
      load16(gA + rowskip, la + 4096);
      load16(gB, lb);
      load16(gB + rowskip, lb + 4096);
      gA += 32; gB += 32;
    }
    // compute from buffer cur
    const short* bufA = sA[cur];
    const short* bufB = sB[cur];
    short8 a[4], bb[4];
    #pragma unroll
    for (int i = 0; i < 4; ++i) {
      a[i]  = *(const short8*)&bufA[(wr * 64 + i * 16 + qm) * 32 + qr * 8];
      bb[i] = *(const short8*)&bufB[(wc * 64 + i * 16 + qm) * 32 + qr * 8];
    }
    #pragma unroll
    for (int mi = 0; mi < 4; ++mi)
      #pragma unroll
      for (int ni = 0; ni < 4; ++ni)
        acc[mi][ni] = __builtin_amdgcn_mfma_f32_16x16x32_bf16(a[mi], bb[ni], acc[mi][ni], 0, 0, 0);
    __syncthreads();  // all waves done reading cur; next-buffer stage drained
    cur ^= 1;
  }

  bf16* outh = (bf16*)outp;
  float* po = (EPI == 4) ? ((z == 0) ? (float*)outp : outp2) : nullptr;
  #pragma unroll
  for (int mi = 0; mi < 4; ++mi) {
    #pragma unroll
    for (int ni = 0; ni < 4; ++ni) {
      const int col = tN + wc * 64 + ni * 16 + qm;
      const float bv = (EPI == 4) ? 0.f : bias[col];
      #pragma unroll
      for (int r = 0; r < 4; ++r) {
        const int row = tM + wr * 64 + mi * 16 + qr * 4 + r;
        const size_t idx = (size_t)row * N + col;
        float v = acc[mi][ni][r] + bv;
        if constexpr (EPI == 4) {
          po[idx] = v;
        } else if constexpr (EPI == 2) {
          v = 0.5f * v * (1.0f + erff(v * 0.70710678118654752f));
          outh[idx] = __float2bfloat16(v);
        } else {
          outh[idx] = __float2bfloat16(v);
        }
      }
    }
  }
  (void)res;
}

// ---------------------------------------------------------------- split-K combine: out = p0+p1+res+bias
// (p0 may alias out: each thread reads its element before writing it)
__global__ __launch_bounds__(256) void splitk_combine(const float* p0,
    const float* __restrict__ p1, const float* __restrict__ res,
    const float* __restrict__ bias, float* out) {
  const int row = blockIdx.x;
  const int tid = threadIdx.x;
  #pragma unroll
  for (int i = 0; i < 3; ++i) {
    const int c = tid + i * 256;
    const size_t idx = (size_t)row * C_EMBD + c;
    out[idx] = p0[idx] + p1[idx] + res[idx] + bias[c];
  }
}

// ---------------------------------------------------------------- flash attention fwd + hidden transposes
// blocks 0..767: attention (round-4/6 structure: swapped QK^T 32x32x16, in-register
//   softmax, KVSPLIT=2, delayed-PV). id -> (qblk = id&31, head = (id>>5)%12, z = id/384).
// blocks 768..5951: transposes of w_ao (576), w_fc (2304), w_proj (2304) — dependency-
//   free until the post-attn GEMMs, so they backfill CU slots as attn blocks retire and
//   execute in attention's shadow (same launch => concurrent; separate launch => serial).
//   Reuses sKb as the 32x33 fp32 tile.
__global__ __launch_bounds__(256, 2) void attn_tr_kernel(const bf16* __restrict__ qkv,
                                                         float* __restrict__ pacc,
                                                         float* __restrict__ pml,
                                                         const float* __restrict__ wB, bf16* __restrict__ oB,
                                                         const float* __restrict__ wC, bf16* __restrict__ oC,
                                                         const float* __restrict__ wD, bf16* __restrict__ oD) {
  __shared__ __align__(16) char sKb[2 * 8192];
  __shared__ __align__(16) char sVb[2 * 8192];
  __shared__ float sRed[4 * 32];

  const int tid = threadIdx.x;
  const int bid = blockIdx.x;

  if (bid >= 768) {
    // ---- transpose path
    int b = bid - 768;
    const float* in; bf16* out; int R, C;
    if (b < 576)       { in = wB; out = oB; R = 768;  C = 768;  }
    else if (b < 2880) { b -= 576;  in = wC; out = oC; R = 768;  C = 3072; }
    else               { b -= 2880; in = wD; out = oD; R = 3072; C = 768;  }
    float (*tile)[33] = (float(*)[33])sKb;
    const int ntx = C / 32;
    const int bx = (b % ntx) * 32;
    const int by = (b / ntx) * 32;
    const int tx = tid & 31, ty = tid >> 5;
    #pragma unroll
    for (int i = 0; i < 32; i += 8)
      tile[ty + i][tx] = in[(size_t)(by + ty + i) * C + bx + tx];
    __syncthreads();
    #pragma unroll
    for (int i = 0; i < 32; i += 8)
      out[(size_t)(bx + ty + i) * R + by + tx] = __float2bfloat16(tile[tx][ty + i]);
    return;
  }

  // ---- attention path
  const int wave = tid >> 6, lane = tid & 63;
  const int qi = lane & 31;
  const int hi = lane >> 5;
  const int hi16 = hi * 16;
  const int head = (bid >> 5) % NHEAD;
  const int z = bid / (32 * NHEAD);
  const int qw = (bid & 31) * 128 + wave * 32;

  short8 qf[4];
  {
    const bf16* qrow = qkv + (size_t)(qw + qi) * C3 + head * 64;
    #pragma unroll
    for (int kd = 0; kd < 4; ++kd) {
      short8 v = *(const short8*)(qrow + kd * 16 + hi * 8);
      #pragma unroll
      for (int i = 0; i < 8; ++i) v[i] = f2bf_bits(bfbits2f(v[i]) * QK_SCALE);
      qf[kd] = v;
    }
  }

  f32x16 acc0 = {}, acc1 = {};
  float m = -3.0e38f, l = 0.f;
  short8 pfrag[4];

  const int nt = (T_SEQ / 64) / KVSPLIT;
  const size_t tilestep = (size_t)64 * C3;
  const size_t zoff = (size_t)z * nt * tilestep;
  const int ksrow = tid >> 3;
  const int kswz = ((tid & 7) ^ (ksrow & 7)) * 8;
  const bf16* gk_base = qkv + zoff + (size_t)ksrow * C3 + C_EMBD + head * 64 + kswz;
  const int vp = tid & 31;
  const int vd0 = (tid >> 5) * 8;
  const bf16* gv_base = qkv + zoff + (size_t)(2 * vp) * C3 + 2 * C_EMBD + head * 64 + vd0;

  const int krow0 = qi * 128;
  const int krow_swz = (qi & 7) << 4;
  const int d1 = 32 + qi;
  const int vs0 = ((qi & 7) ^ ((qi >> 3) & 7)) << 4;
  const int vs1 = ((d1 & 7) ^ ((d1 >> 3) & 7)) << 4;

  short8 v0 = *(const short8*)gv_base;
  short8 v1 = *(const short8*)(gv_base + C3);
  load16(gk_base, sKb + wave * 1024);
  load16(gk_base + (size_t)32 * C3, sKb + wave * 1024 + 4096);

  for (int t = 0; t < nt; ++t) {
    const int cur = t & 1;
    char* bK = sKb + cur * 8192;
    char* bV = sVb + cur * 8192;

    __syncthreads();

    #pragma unroll
    for (int j = 0; j < 8; ++j) {
      const int d = vd0 + j;
      const int vs = ((d & 7) ^ ((d >> 3) & 7)) << 4;
      const uint32_t packed = (uint32_t)(unsigned short)v0[j] |
                              ((uint32_t)(unsigned short)v1[j] << 16);
      *(uint32_t*)(bV + d * 128 + ((vp * 4) ^ vs)) = packed;
    }

    if (t + 1 < nt) {
      const bf16* gv = gv_base + (size_t)(t + 1) * tilestep;
      v0 = *(const short8*)gv;
      v1 = *(const short8*)(gv + C3);
      const bf16* gk = gk_base + (size_t)(t + 1) * tilestep;
      char* bKn = sKb + (cur ^ 1) * 8192;
      load16(gk, bKn + wave * 1024);
      load16(gk + (size_t)32 * C3, bKn + wave * 1024 + 4096);
    }

    f32x16 s0 = {}, s1 = {};
    __builtin_amdgcn_s_setprio(1);
    #pragma unroll
    for (int kd = 0; kd < 4; ++kd) {
      const int off = (kd * 32 + hi16) ^ krow_swz;
      short8 ka0 = *(const short8*)(bK + krow0 + off);
      short8 ka1 = *(const short8*)(bK + 4096 + krow0 + off);
      s0 = __builtin_amdgcn_mfma_f32_32x32x16_bf16(ka0, qf[kd], s0, 0, 0, 0);
      s1 = __builtin_amdgcn_mfma_f32_32x32x16_bf16(ka1, qf[kd], s1, 0, 0, 0);
    }

    if (t > 0) {
      char* bVp = sVb + (cur ^ 1) * 8192;
      #pragma unroll
      for (int kk = 0; kk < 4; ++kk) {
        const int voff = (kk * 32 + hi16);
        short8 vb0 = *(const short8*)(bVp + qi * 128 + (voff ^ vs0));
        short8 vb1 = *(const short8*)(bVp + d1 * 128 + (voff ^ vs1));
        acc0 = __builtin_amdgcn_mfma_f32_32x32x16_bf16(pfrag[kk], vb0, acc0, 0, 0, 0);
        acc1 = __builtin_amdgcn_mfma_f32_32x32x16_bf16(pfrag[kk], vb1, acc1, 0, 0, 0);
      }
    }
    __builtin_amdgcn_s_setprio(0);

    float t8[8];
    #pragma unroll
    for (int i = 0; i < 8; ++i) t8[i] = max3f(s0[i], s0[i + 8], s1[i]);
    float t4[4];
    #pragma unroll
    for (int i = 0; i < 4; ++i) t4[i] = max3f(t8[2 * i], t8[2 * i + 1], s1[8 + i]);
    float t2[2];
    #pragma unroll
    for (int i = 0; i < 2; ++i) t2[i] = max3f(t4[2 * i], t4[2 * i + 1], s1[12 + i]);
    const float t1 = max3f(t2[0], t2[1], s1[14]);
    const float tmx = fmaxf(t1, s1[15]);
    float pmax;
    {
      float a0 = tmx, a1 = tmx;
      asm("v_permlane32_swap_b32 %0, %1" : "+v"(a0), "+v"(a1));
      pmax = fmaxf(a0, a1);
    }

    if (__any(pmax - m > 8.0f)) {
      const float mn = fmaxf(m, pmax);
      const float sc = expx(m - mn);
      l *= sc;
      if (lane < 32) sRed[wave * 32 + qi] = sc;
      #pragma unroll
      for (int r = 0; r < 16; ++r) {
        const float sv = sRed[wave * 32 + ((r & 3) + 8 * (r >> 2) + hi * 4)];
        acc0[r] *= sv; acc1[r] *= sv;
      }
      m = mn;
    }

    float red[16];
    #pragma unroll
    for (int r = 0; r < 16; ++r) { s0[r] = expx(s0[r] - m); s1[r] = expx(s1[r] - m); }
    #pragma unroll
    for (int r = 0; r < 16; ++r) red[r] = s0[r] + s1[r];
    #pragma unroll
    for (int w = 8; w >= 1; w >>= 1)
      #pragma unroll
      for (int r = 0; r < w; ++r) red[r] += red[r + w];
    {
      float a0 = red[0], a1 = red[0];
      asm("v_permlane32_swap_b32 %0, %1" : "+v"(a0), "+v"(a1));
      l += a0 + a1;
    }

    #pragma unroll
    for (int b = 0; b < 2; ++b) {
      const f32x16 sb = b ? s1 : s0;
      uint32_t pk[8];
      #pragma unroll
      for (int g = 0; g < 4; ++g) {
        asm("v_cvt_pk_bf16_f32 %0, %1, %2" : "=v"(pk[2 * g])     : "v"(sb[4 * g + 0]), "v"(sb[4 * g + 1]));
        asm("v_cvt_pk_bf16_f32 %0, %1, %2" : "=v"(pk[2 * g + 1]) : "v"(sb[4 * g + 2]), "v"(sb[4 * g + 3]));
      }
      #pragma unroll
      for (int kbl = 0; kbl < 2; ++kbl) {
        uint32_t w0 = pk[4 * kbl + 0], w2 = pk[4 * kbl + 2];
        asm("v_permlane32_swap_b32 %0, %1" : "+v"(w0), "+v"(w2));
        uint32_t w1 = pk[4 * kbl + 1], w3 = pk[4 * kbl + 3];
        asm("v_permlane32_swap_b32 %0, %1" : "+v"(w1), "+v"(w3));
        union { uint32_t u[4]; short8 v; } pu;
        pu.u[0] = w0; pu.u[1] = w1; pu.u[2] = w2; pu.u[3] = w3;
        pfrag[b * 2 + kbl] = pu.v;
      }
    }
  }

  __syncthreads();
  {
    char* bVl = sVb + ((nt - 1) & 1) * 8192;
    __builtin_amdgcn_s_setprio(1);
    #pragma unroll
    for (int kk = 0; kk < 4; ++kk) {
      const int voff = (kk * 32 + hi16);
      short8 vb0 = *(const short8*)(bVl + qi * 128 + (voff ^ vs0));
      short8 vb1 = *(const short8*)(bVl + d1 * 128 + (voff ^ vs1));
      acc0 = __builtin_amdgcn_mfma_f32_32x32x16_bf16(pfrag[kk], vb0, acc0, 0, 0, 0);
      acc1 = __builtin_amdgcn_mfma_f32_32x32x16_bf16(pfrag[kk], vb1, acc1, 0, 0, 0);
    }
    __builtin_amdgcn_s_setprio(0);
  }

  float* pa = pacc + ((size_t)z * T_SEQ + qw) * C_EMBD + head * 64;
  #pragma unroll
  for (int r = 0; r < 16; ++r) {
    const int q = (r & 3) + 8 * (r >> 2) + hi * 4;
    pa[(size_t)q * C_EMBD + qi]      = acc0[r];
    pa[(size_t)q * C_EMBD + 32 + qi] = acc1[r];
  }
  if (lane < 32) {
    float2* mlp = (float2*)pml;
    mlp[((size_t)z * NHEAD + head) * T_SEQ + qw + qi] = make_float2(m, l);
  }
}

// ---------------------------------------------------------------- combine the KV splits
__global__ __launch_bounds__(256) void attn_combine(const float* __restrict__ pacc,
    const float* __restrict__ pml, bf16* __restrict__ out) {
  const int q = blockIdx.x;
  const int tid = threadIdx.x;
  const float2* mlp = (const float2*)pml;
  #pragma unroll
  for (int i = 0; i < 3; ++i) {
    const int c = tid + i * 256;
    const int h = c >> 6;
    const float2 ml0 = mlp[(size_t)h * T_SEQ + q];
    const float2 ml1 = mlp[((size_t)NHEAD + h) * T_SEQ + q];
    const float M = fmaxf(ml0.x, ml1.x);
    const float w0 = expx(ml0.x - M), w1 = expx(ml1.x - M);
    const float inv = 1.0f / (ml0.y * w0 + ml1.y * w1);
    const float a0 = pacc[(size_t)q * C_EMBD + c];
    const float a1 = pacc[(size_t)T_SEQ * C_EMBD + (size_t)q * C_EMBD + c];
    out[(size_t)q * C_EMBD + c] = __float2bfloat16((a0 * w0 + a1 * w1) * inv);
  }
}

// ---------------------------------------------------------------- launch
extern "C" void kernel_launch(void* const* d_in, const int* in_sizes, int n_in,
                              void* d_out, int out_size, void* d_ws, size_t ws_size,
                              hipStream_t stream) {
  const float* x      = (const float*)d_in[0];
  const float* ln1_g  = (const float*)d_in[1];
  const float* ln1_b  = (const float*)d_in[2];
  const float* w_attn = (const float*)d_in[3];
  const float* b_attn = (const float*)d_in[4];
  const float* w_ao   = (const float*)d_in[5];
  const float* b_ao   = (const float*)d_in[6];
  const float* ln2_g  = (const float*)d_in[7];
  const float* ln2_b  = (const float*)d_in[8];
  const float* w_fc   = (const float*)d_in[9];
  const float* b_fc   = (const float*)d_in[10];
  const float* w_proj = (const float*)d_in[11];
  const float* b_proj = (const float*)d_in[12];

  char* ws = (char*)d_ws;
  size_t off = 0;
  auto alloc = [&](size_t nbytes) {
    char* p = ws + off;
    off += (nbytes + 255) & ~(size_t)255;
    return p;
  };
  bf16* wT_attn = (bf16*)alloc((size_t)C3 * C_EMBD * 2);        // [2304][768]
  bf16* wT_ao   = (bf16*)alloc((size_t)C_EMBD * C_EMBD * 2);    // [768][768]
  bf16* wT_fc   = (bf16*)alloc((size_t)4 * C_EMBD * C_EMBD * 2);// [3072][768]
  bf16* wT_proj = (bf16*)alloc((size_t)C_EMBD * 4 * C_EMBD * 2);// [768][3072]
  bf16* h       = (bf16*)alloc((size_t)T_SEQ * C_EMBD * 2);     // ln out (reused)
  bf16* qkv     = (bf16*)alloc((size_t)T_SEQ * C3 * 2);
  bf16* y       = (bf16*)alloc((size_t)T_SEQ * C_EMBD * 2);     // attn out
  float* x1     = (float*)alloc((size_t)T_SEQ * C_EMBD * 4);    // residual 1
  bf16* hf      = (bf16*)alloc((size_t)T_SEQ * 4 * C_EMBD * 2); // gelu out
  float* pml    = (float*)alloc((size_t)KVSPLIT * NHEAD * T_SEQ * 2 * 4); // (m,l) partials
  // Scratch lifetime plan (all aliases of buffers dead at time of use):
  //  - attn partials pacc -> hf (consumed by attn_combine, before ao GEMM)
  //  - ao split-K partials pa0/pa1 -> hf, hf+T*C floats (consumed by ln2_fused,
  //    then hf is rewritten by the fc GEMM)
  //  - proj split-K partials pp0 -> d_out, pp1 -> qkv (consumed by splitk_combine)
  float* pacc   = (float*)hf;
  float* pa0    = (float*)hf;
  float* pa1    = (float*)hf + (size_t)T_SEQ * C_EMBD;
  float* pp0    = (float*)d_out;
  float* pp1    = (float*)qkv;
  (void)ws_size; (void)in_sizes; (void)n_in; (void)out_size;

  // w_attn transpose + ln1 (only what the qkv GEMM needs)
  transpose1_ln_kernel<<<1728 + T_SEQ, 256, 0, stream>>>(w_attn, wT_attn, x, ln1_g, ln1_b, h);

  // qkv = h @ w_attn + b_attn  (bf16 out)
  gemm_bt<0><<<dim3(C3 / 128, T_SEQ / 128), 256, 0, stream>>>(h, wT_attn, b_attn, nullptr, qkv,
                                                              nullptr, T_SEQ, C3, C_EMBD, C_EMBD);
  // attention (768 blocks) + hidden transposes of w_ao/w_fc/w_proj (5184 blocks)
  attn_tr_kernel<<<768 + 5184, 256, 0, stream>>>(qkv, pacc, pml,
                                                 w_ao, wT_ao, w_fc, wT_fc, w_proj, wT_proj);
  attn_combine<<<T_SEQ, 256, 0, stream>>>(pacc, pml, y);
  // ao: split-K=2 deterministic partials (pa0/pa1 -> hf scratch)
  gemm_bt<4><<<dim3(C_EMBD / 128, T_SEQ / 128, 2), 256, 0, stream>>>(y, wT_ao, nullptr, nullptr,
                                                                     pa0, pa1, T_SEQ, C_EMBD,
                                                                     C_EMBD / 2, C_EMBD);
  // ln2 fused with ao combine: x1 = pa0+pa1+x+b_ao ; h = LN(x1)
  ln2_fused_kernel<<<T_SEQ, 256, 0, stream>>>(pa0, pa1, x, b_ao, ln2_g, ln2_b, h, x1);
  // hf = gelu(h @ w_fc + b_fc)  (bf16 out)
  gemm_bt<2><<<dim3(4 * C_EMBD / 128, T_SEQ / 128), 256, 0, stream>>>(h, wT_fc, b_fc, nullptr, hf,
                                                                      nullptr, T_SEQ, 4 * C_EMBD,
                                                                      C_EMBD, C_EMBD);
  // proj: split-K=2 deterministic partials (z0 -> d_out scratch, z1 -> qkv scratch)
  gemm_bt<4><<<dim3(C_EMBD / 128, T_SEQ / 128, 2), 256, 0, stream>>>(hf, wT_proj, nullptr, nullptr,
                                                                     pp0, pp1, T_SEQ, C_EMBD,
                                                                     2 * C_EMBD, 4 * C_EMBD);
  // out = p0 + p1 + x1 + b_proj
  splitk_combine<<<T_SEQ, 256, 0, stream>>>(pp0, pp1, x1, b_proj, (float*)d_out);
}

// Round 14
// 216.361 us; speedup vs baseline: 1.0764x; 1.0022x over previous
//
#include <hip/hip_runtime.h>
#include <hip/hip_bf16.h>
#include <cstdint>
#include <cstddef>

typedef __hip_bfloat16 bf16;
typedef __attribute__((ext_vector_type(8))) short short8;
typedef __attribute__((ext_vector_type(4))) float f32x4;
typedef __attribute__((ext_vector_type(16))) float f32x16;

#define C_EMBD 768
#define C3     2304
#define T_SEQ  4096
#define NHEAD  12
#define KVSPLIT 2

// ---------------------------------------------------------------- helpers
__device__ __forceinline__ void load16(const void* g, void* lds) {
  __builtin_amdgcn_global_load_lds(
      (const __attribute__((address_space(1))) uint32_t*)g,
      (__attribute__((address_space(3))) uint32_t*)lds, 16, 0, 0);
}

__device__ __forceinline__ short f2bf_bits(float x) {
  union { bf16 h; short s; } u; u.h = __float2bfloat16(x); return u.s;
}

__device__ __forceinline__ float bfbits2f(short s) {
  union { uint32_t u; float f; } u; u.u = ((uint32_t)(unsigned short)s) << 16; return u.f;
}

__device__ __forceinline__ float max3f(float a, float b, float c) {
  float d;
  asm("v_max3_f32 %0, %1, %2, %3" : "=v"(d) : "v"(a), "v"(b), "v"(c));
  return d;
}

// exp in log2-domain when native exp2 builtin is available (folds log2e into Q scale)
#if __has_builtin(__builtin_amdgcn_exp2f)
#define QK_SCALE (0.125f * 1.44269504088896340736f)
__device__ __forceinline__ float expx(float x) { return __builtin_amdgcn_exp2f(x); }
#else
#define QK_SCALE 0.125f
__device__ __forceinline__ float expx(float x) { return __expf(x); }
#endif

// ---------------------------------------------------------------- LN2 fused with ao split-K combine:
// xv = pa0 + pa1 + x + b_ao ; x1 = xv ; out = bf16(LN(xv))
__global__ __launch_bounds__(256) void ln2_fused_kernel(
    const float* __restrict__ pa0, const float* __restrict__ pa1,
    const float* __restrict__ x, const float* __restrict__ b_ao,
    const float* __restrict__ g, const float* __restrict__ b,
    bf16* __restrict__ out, float* __restrict__ x1) {
  const int row = blockIdx.x;
  const int tid = threadIdx.x;
  const int lane = tid & 63, wave = tid >> 6;
  float v[3];
  #pragma unroll
  for (int i = 0; i < 3; ++i) {
    const int c = tid + i * 256;
    const size_t idx = (size_t)row * C_EMBD + c;
    v[i] = pa0[idx] + pa1[idx] + x[idx] + b_ao[c];
    x1[idx] = v[i];
  }
  float s = v[0] + v[1] + v[2];
  #pragma unroll
  for (int o = 1; o < 64; o <<= 1) s += __shfl_xor(s, o, 64);
  __shared__ float red[4];
  if (lane == 0) red[wave] = s;
  __syncthreads();
  const float mu = (red[0] + red[1] + red[2] + red[3]) * (1.0f / C_EMBD);
  float d0 = v[0] - mu, d1 = v[1] - mu, d2 = v[2] - mu;
  float q = d0 * d0 + d1 * d1 + d2 * d2;
  #pragma unroll
  for (int o = 1; o < 64; o <<= 1) q += __shfl_xor(q, o, 64);
  __syncthreads();
  if (lane == 0) red[wave] = q;
  __syncthreads();
  const float var = (red[0] + red[1] + red[2] + red[3]) * (1.0f / C_EMBD);
  const float rs = rsqrtf(var + 1e-5f);
  #pragma unroll
  for (int i = 0; i < 3; ++i) {
    int c = tid + i * 256;
    out[(size_t)row * C_EMBD + c] = __float2bfloat16((v[i] - mu) * rs * g[c] + b[c]);
  }
}

// ---------------------------------------------------------------- w_attn transpose + ln1
// blocks 0..1727: w_attn 768x2304 fp32 -> bf16 [2304][768]
// blocks 1728..5823: ln1 rows (4096) — h = bf16(LN(x))
__global__ __launch_bounds__(256) void transpose1_ln_kernel(
    const float* __restrict__ wA, bf16* __restrict__ oA,
    const float* __restrict__ x, const float* __restrict__ lg,
    const float* __restrict__ lb, bf16* __restrict__ oh) {
  __shared__ float tile[32][33];
  __shared__ float red[4];
  int b = blockIdx.x;
  const int tid = threadIdx.x;
  if (b >= 1728) {
    // ---- LN1 path
    const int row = b - 1728;
    const int lane = tid & 63, wave = tid >> 6;
    const float* xr = x + (size_t)row * C_EMBD;
    float v[3];
    #pragma unroll
    for (int i = 0; i < 3; ++i) v[i] = xr[tid + i * 256];
    float s = v[0] + v[1] + v[2];
    #pragma unroll
    for (int o = 1; o < 64; o <<= 1) s += __shfl_xor(s, o, 64);
    if (lane == 0) red[wave] = s;
    __syncthreads();
    const float mu = (red[0] + red[1] + red[2] + red[3]) * (1.0f / C_EMBD);
    float d0 = v[0] - mu, d1 = v[1] - mu, d2 = v[2] - mu;
    float q = d0 * d0 + d1 * d1 + d2 * d2;
    #pragma unroll
    for (int o = 1; o < 64; o <<= 1) q += __shfl_xor(q, o, 64);
    __syncthreads();
    if (lane == 0) red[wave] = q;
    __syncthreads();
    const float var = (red[0] + red[1] + red[2] + red[3]) * (1.0f / C_EMBD);
    const float rs = rsqrtf(var + 1e-5f);
    #pragma unroll
    for (int i = 0; i < 3; ++i) {
      int c = tid + i * 256;
      oh[(size_t)row * C_EMBD + c] = __float2bfloat16((v[i] - mu) * rs * lg[c] + lb[c]);
    }
    return;
  }
  // ---- transpose path (w_attn: R=768, C=2304)
  const int ntx = C3 / 32;
  const int bx = (b % ntx) * 32;
  const int by = (b / ntx) * 32;
  const int tx = tid & 31, ty = tid >> 5;
  #pragma unroll
  for (int i = 0; i < 32; i += 8)
    tile[ty + i][tx] = wA[(size_t)(by + ty + i) * C3 + bx + tx];
  __syncthreads();
  #pragma unroll
  for (int i = 0; i < 32; i += 8)
    oA[(size_t)(bx + ty + i) * C_EMBD + by + tx] = __float2bfloat16(tile[tx][ty + i]);
}

// ---------------------------------------------------------------- GEMM: A[M][K] bf16 x BT[N][K] bf16
// Round-9 structure (16x16x32 MFMA, 2-phase dbuf, launch_bounds(256,3)) + T1 XCD-aware
// chunked block swizzle (bijective: all grids have nwg % 8 == 0).
// EPI 0: out = bf16(acc + bias)
// EPI 2: out = bf16(gelu(acc + bias))
// EPI 4: split-K over blockIdx.z (deterministic): z==0 -> outp, z==1 -> outp2, raw f32 acc
template <int EPI>
__global__ __launch_bounds__(256, 3) void gemm_bt(
    const bf16* __restrict__ A, const bf16* __restrict__ BT,
    const float* __restrict__ bias, const float* __restrict__ res,
    void* __restrict__ outp, float* __restrict__ outp2, int M, int N, int Ks, int Kst) {
  __shared__ __align__(16) short sA[2][128 * 32];
  __shared__ __align__(16) short sB[2][128 * 32];
  const int tid = threadIdx.x;
  const int wave = tid >> 6, lane = tid & 63;
  const int qr = lane >> 4, qm = lane & 15;
  const int wr = wave >> 1, wc = wave & 1;
  // XCD-aware chunked swizzle of the (x,y) block id (z untouched)
  const int gx = gridDim.x;
  int flat = blockIdx.y * gx + blockIdx.x;
  const int cpx = (gx * gridDim.y) >> 3;  // nwg/8, exact for all our grids
  flat = (flat & 7) * cpx + (flat >> 3);
  const int tM = (flat / gx) * 128, tN = (flat % gx) * 128;
  const int z = (EPI == 4) ? blockIdx.z : 0;

  f32x4 acc[4][4] = {};

  const int srow = tid >> 2;
  const int scol = (tid & 3) * 8;
  const bf16* gA = A + (size_t)z * Ks + (size_t)(tM + srow) * Kst + scol;
  const bf16* gB = BT + (size_t)z * Ks + (size_t)(tN + srow) * Kst + scol;
  const int woff = wave * 1024;
  const size_t rowskip = (size_t)64 * Kst;

  const int nk = Ks >> 5;
  // prologue: stage k-step 0 into buffer 0
  {
    char* la = (char*)sA[0] + woff;
    char* lb = (char*)sB[0] + woff;
    load16(gA, la);
    load16(gA + rowskip, la + 4096);
    load16(gB, lb);
    load16(gB + rowskip, lb + 4096);
    gA += 32; gB += 32;
  }
  __syncthreads();  // prologue loads drained

  int cur = 0;
  for (int k0 = 0; k0 < nk; ++k0) {
    // issue stage of k-step k0+1 into the other buffer (overlaps compute below)
    if (k0 + 1 < nk) {
      char* la = (char*)sA[cur ^ 1] + woff;
      char* lb = (char*)sB[cur ^ 1] + woff;
      load16(gA, la);
      load16(gA + rowskip, la + 4096);
      load16(gB, lb);
      load16(gB + rowskip, lb + 4096);
      gA += 32; gB += 32;
    }
    // compute from buffer cur
    const short* bufA = sA[cur];
    const short* bufB = sB[cur];
    short8 a[4], bb[4];
    #pragma unroll
    for (int i = 0; i < 4; ++i) {
      a[i]  = *(const short8*)&bufA[(wr * 64 + i * 16 + qm) * 32 + qr * 8];
      bb[i] = *(const short8*)&bufB[(wc * 64 + i * 16 + qm) * 32 + qr * 8];
    }
    #pragma unroll
    for (int mi = 0; mi < 4; ++mi)
      #pragma unroll
      for (int ni = 0; ni < 4; ++ni)
        acc[mi][ni] = __builtin_amdgcn_mfma_f32_16x16x32_bf16(a[mi], bb[ni], acc[mi][ni], 0, 0, 0);
    __syncthreads();  // all waves done reading cur; next-buffer stage drained
    cur ^= 1;
  }

  bf16* outh = (bf16*)outp;
  float* po = (EPI == 4) ? ((z == 0) ? (float*)outp : outp2) : nullptr;
  #pragma unroll
  for (int mi = 0; mi < 4; ++mi) {
    #pragma unroll
    for (int ni = 0; ni < 4; ++ni) {
      const int col = tN + wc * 64 + ni * 16 + qm;
      const float bv = (EPI == 4) ? 0.f : bias[col];
      #pragma unroll
      for (int r = 0; r < 4; ++r) {
        const int row = tM + wr * 64 + mi * 16 + qr * 4 + r;
        const size_t idx = (size_t)row * N + col;
        float v = acc[mi][ni][r] + bv;
        if constexpr (EPI == 4) {
          po[idx] = v;
        } else if constexpr (EPI == 2) {
          v = 0.5f * v * (1.0f + erff(v * 0.70710678118654752f));
          outh[idx] = __float2bfloat16(v);
        } else {
          outh[idx] = __float2bfloat16(v);
        }
      }
    }
  }
  (void)res;
}

// ---------------------------------------------------------------- split-K combine: out = p0+p1+res+bias
// (p0 may alias out: each thread reads its element before writing it)
__global__ __launch_bounds__(256) void splitk_combine(const float* p0,
    const float* __restrict__ p1, const float* __restrict__ res,
    const float* __restrict__ bias, float* out) {
  const int row = blockIdx.x;
  const int tid = threadIdx.x;
  #pragma unroll
  for (int i = 0; i < 3; ++i) {
    const int c = tid + i * 256;
    const size_t idx = (size_t)row * C_EMBD + c;
    out[idx] = p0[idx] + p1[idx] + res[idx] + bias[c];
  }
}

// ---------------------------------------------------------------- flash attention fwd + hidden transposes
// blocks 0..767: attention (round-4/6 structure), with an XCD-aware chunked swizzle on
//   the attention work id: each XCD gets 96 contiguous work ids = one z-half x 3 heads
//   x 32 q-blocks -> unique K/V per XCD ~1.5MB, fully L2-resident (was: all heads/z per
//   XCD, 19MB > 4MB L2).
// blocks 768..5951: transposes of w_ao (576), w_fc (2304), w_proj (2304) — dependency-
//   free until the post-attn GEMMs; backfill CU slots as attn blocks retire.
__global__ __launch_bounds__(256, 2) void attn_tr_kernel(const bf16* __restrict__ qkv,
                                                         float* __restrict__ pacc,
                                                         float* __restrict__ pml,
                                                         const float* __restrict__ wB, bf16* __restrict__ oB,
                                                         const float* __restrict__ wC, bf16* __restrict__ oC,
                                                         const float* __restrict__ wD, bf16* __restrict__ oD) {
  __shared__ __align__(16) char sKb[2 * 8192];
  __shared__ __align__(16) char sVb[2 * 8192];
  __shared__ float sRed[4 * 32];

  const int tid = threadIdx.x;
  const int bid = blockIdx.x;

  if (bid >= 768) {
    // ---- transpose path
    int b = bid - 768;
    const float* in; bf16* out; int R, C;
    if (b < 576)       { in = wB; out = oB; R = 768;  C = 768;  }
    else if (b < 2880) { b -= 576;  in = wC; out = oC; R = 768;  C = 3072; }
    else               { b -= 2880; in = wD; out = oD; R = 3072; C = 768;  }
    float (*tile)[33] = (float(*)[33])sKb;
    const int ntx = C / 32;
    const int bx = (b % ntx) * 32;
    const int by = (b / ntx) * 32;
    const int tx = tid & 31, ty = tid >> 5;
    #pragma unroll
    for (int i = 0; i < 32; i += 8)
      tile[ty + i][tx] = in[(size_t)(by + ty + i) * C + bx + tx];
    __syncthreads();
    #pragma unroll
    for (int i = 0; i < 32; i += 8)
      out[(size_t)(bx + ty + i) * R + by + tx] = __float2bfloat16(tile[tx][ty + i]);
    return;
  }

  // ---- attention path (XCD-chunked work id: 768 % 8 == 0, bijective)
  const int wid = (bid & 7) * 96 + (bid >> 3);
  const int wave = tid >> 6, lane = tid & 63;
  const int qi = lane & 31;
  const int hi = lane >> 5;
  const int hi16 = hi * 16;
  const int head = (wid >> 5) % NHEAD;
  const int z = wid / (32 * NHEAD);
  const int qw = (wid & 31) * 128 + wave * 32;

  short8 qf[4];
  {
    const bf16* qrow = qkv + (size_t)(qw + qi) * C3 + head * 64;
    #pragma unroll
    for (int kd = 0; kd < 4; ++kd) {
      short8 v = *(const short8*)(qrow + kd * 16 + hi * 8);
      #pragma unroll
      for (int i = 0; i < 8; ++i) v[i] = f2bf_bits(bfbits2f(v[i]) * QK_SCALE);
      qf[kd] = v;
    }
  }

  f32x16 acc0 = {}, acc1 = {};
  float m = -3.0e38f, l = 0.f;
  short8 pfrag[4];

  const int nt = (T_SEQ / 64) / KVSPLIT;
  const size_t tilestep = (size_t)64 * C3;
  const size_t zoff = (size_t)z * nt * tilestep;
  const int ksrow = tid >> 3;
  const int kswz = ((tid & 7) ^ (ksrow & 7)) * 8;
  const bf16* gk_base = qkv + zoff + (size_t)ksrow * C3 + C_EMBD + head * 64 + kswz;
  const int vp = tid & 31;
  const int vd0 = (tid >> 5) * 8;
  const bf16* gv_base = qkv + zoff + (size_t)(2 * vp) * C3 + 2 * C_EMBD + head * 64 + vd0;

  const int krow0 = qi * 128;
  const int krow_swz = (qi & 7) << 4;
  const int d1 = 32 + qi;
  const int vs0 = ((qi & 7) ^ ((qi >> 3) & 7)) << 4;
  const int vs1 = ((d1 & 7) ^ ((d1 >> 3) & 7)) << 4;

  short8 v0 = *(const short8*)gv_base;
  short8 v1 = *(const short8*)(gv_base + C3);
  load16(gk_base, sKb + wave * 1024);
  load16(gk_base + (size_t)32 * C3, sKb + wave * 1024 + 4096);

  for (int t = 0; t < nt; ++t) {
    const int cur = t & 1;
    char* bK = sKb + cur * 8192;
    char* bV = sVb + cur * 8192;

    __syncthreads();

    #pragma unroll
    for (int j = 0; j < 8; ++j) {
      const int d = vd0 + j;
      const int vs = ((d & 7) ^ ((d >> 3) & 7)) << 4;
      const uint32_t packed = (uint32_t)(unsigned short)v0[j] |
                              ((uint32_t)(unsigned short)v1[j] << 16);
      *(uint32_t*)(bV + d * 128 + ((vp * 4) ^ vs)) = packed;
    }

    if (t + 1 < nt) {
      const bf16* gv = gv_base + (size_t)(t + 1) * tilestep;
      v0 = *(const short8*)gv;
      v1 = *(const short8*)(gv + C3);
      const bf16* gk = gk_base + (size_t)(t + 1) * tilestep;
      char* bKn = sKb + (cur ^ 1) * 8192;
      load16(gk, bKn + wave * 1024);
      load16(gk + (size_t)32 * C3, bKn + wave * 1024 + 4096);
    }

    f32x16 s0 = {}, s1 = {};
    __builtin_amdgcn_s_setprio(1);
    #pragma unroll
    for (int kd = 0; kd < 4; ++kd) {
      const int off = (kd * 32 + hi16) ^ krow_swz;
      short8 ka0 = *(const short8*)(bK + krow0 + off);
      short8 ka1 = *(const short8*)(bK + 4096 + krow0 + off);
      s0 = __builtin_amdgcn_mfma_f32_32x32x16_bf16(ka0, qf[kd], s0, 0, 0, 0);
      s1 = __builtin_amdgcn_mfma_f32_32x32x16_bf16(ka1, qf[kd], s1, 0, 0, 0);
    }

    if (t > 0) {
      char* bVp = sVb + (cur ^ 1) * 8192;
      #pragma unroll
      for (int kk = 0; kk < 4; ++kk) {
        const int voff = (kk * 32 + hi16);
        short8 vb0 = *(const short8*)(bVp + qi * 128 + (voff ^ vs0));
        short8 vb1 = *(const short8*)(bVp + d1 * 128 + (voff ^ vs1));
        acc0 = __builtin_amdgcn_mfma_f32_32x32x16_bf16(pfrag[kk], vb0, acc0, 0, 0, 0);
        acc1 = __builtin_amdgcn_mfma_f32_32x32x16_bf16(pfrag[kk], vb1, acc1, 0, 0, 0);
      }
    }
    __builtin_amdgcn_s_setprio(0);

    float t8[8];
    #pragma unroll
    for (int i = 0; i < 8; ++i) t8[i] = max3f(s0[i], s0[i + 8], s1[i]);
    float t4[4];
    #pragma unroll
    for (int i = 0; i < 4; ++i) t4[i] = max3f(t8[2 * i], t8[2 * i + 1], s1[8 + i]);
    float t2[2];
    #pragma unroll
    for (int i = 0; i < 2; ++i) t2[i] = max3f(t4[2 * i], t4[2 * i + 1], s1[12 + i]);
    const float t1 = max3f(t2[0], t2[1], s1[14]);
    const float tmx = fmaxf(t1, s1[15]);
    float pmax;
    {
      float a0 = tmx, a1 = tmx;
      asm("v_permlane32_swap_b32 %0, %1" : "+v"(a0), "+v"(a1));
      pmax = fmaxf(a0, a1);
    }

    if (__any(pmax - m > 8.0f)) {
      const float mn = fmaxf(m, pmax);
      const float sc = expx(m - mn);
      l *= sc;
      if (lane < 32) sRed[wave * 32 + qi] = sc;
      #pragma unroll
      for (int r = 0; r < 16; ++r) {
        const float sv = sRed[wave * 32 + ((r & 3) + 8 * (r >> 2) + hi * 4)];
        acc0[r] *= sv; acc1[r] *= sv;
      }
      m = mn;
    }

    float red[16];
    #pragma unroll
    for (int r = 0; r < 16; ++r) { s0[r] = expx(s0[r] - m); s1[r] = expx(s1[r] - m); }
    #pragma unroll
    for (int r = 0; r < 16; ++r) red[r] = s0[r] + s1[r];
    #pragma unroll
    for (int w = 8; w >= 1; w >>= 1)
      #pragma unroll
      for (int r = 0; r < w; ++r) red[r] += red[r + w];
    {
      float a0 = red[0], a1 = red[0];
      asm("v_permlane32_swap_b32 %0, %1" : "+v"(a0), "+v"(a1));
      l += a0 + a1;
    }

    #pragma unroll
    for (int b = 0; b < 2; ++b) {
      const f32x16 sb = b ? s1 : s0;
      uint32_t pk[8];
      #pragma unroll
      for (int g = 0; g < 4; ++g) {
        asm("v_cvt_pk_bf16_f32 %0, %1, %2" : "=v"(pk[2 * g])     : "v"(sb[4 * g + 0]), "v"(sb[4 * g + 1]));
        asm("v_cvt_pk_bf16_f32 %0, %1, %2" : "=v"(pk[2 * g + 1]) : "v"(sb[4 * g + 2]), "v"(sb[4 * g + 3]));
      }
      #pragma unroll
      for (int kbl = 0; kbl < 2; ++kbl) {
        uint32_t w0 = pk[4 * kbl + 0], w2 = pk[4 * kbl + 2];
        asm("v_permlane32_swap_b32 %0, %1" : "+v"(w0), "+v"(w2));
        uint32_t w1 = pk[4 * kbl + 1], w3 = pk[4 * kbl + 3];
        asm("v_permlane32_swap_b32 %0, %1" : "+v"(w1), "+v"(w3));
        union { uint32_t u[4]; short8 v; } pu;
        pu.u[0] = w0; pu.u[1] = w1; pu.u[2] = w2; pu.u[3] = w3;
        pfrag[b * 2 + kbl] = pu.v;
      }
    }
  }

  __syncthreads();
  {
    char* bVl = sVb + ((nt - 1) & 1) * 8192;
    __builtin_amdgcn_s_setprio(1);
    #pragma unroll
    for (int kk = 0; kk < 4; ++kk) {
      const int voff = (kk * 32 + hi16);
      short8 vb0 = *(const short8*)(bVl + qi * 128 + (voff ^ vs0));
      short8 vb1 = *(const short8*)(bVl + d1 * 128 + (voff ^ vs1));
      acc0 = __builtin_amdgcn_mfma_f32_32x32x16_bf16(pfrag[kk], vb0, acc0, 0, 0, 0);
      acc1 = __builtin_amdgcn_mfma_f32_32x32x16_bf16(pfrag[kk], vb1, acc1, 0, 0, 0);
    }
    __builtin_amdgcn_s_setprio(0);
  }

  float* pa = pacc + ((size_t)z * T_SEQ + qw) * C_EMBD + head * 64;
  #pragma unroll
  for (int r = 0; r < 16; ++r) {
    const int q = (r & 3) + 8 * (r >> 2) + hi * 4;
    pa[(size_t)q * C_EMBD + qi]      = acc0[r];
    pa[(size_t)q * C_EMBD + 32 + qi] = acc1[r];
  }
  if (lane < 32) {
    float2* mlp = (float2*)pml;
    mlp[((size_t)z * NHEAD + head) * T_SEQ + qw + qi] = make_float2(m, l);
  }
}

// ---------------------------------------------------------------- combine the KV splits
__global__ __launch_bounds__(256) void attn_combine(const float* __restrict__ pacc,
    const float* __restrict__ pml, bf16* __restrict__ out) {
  const int q = blockIdx.x;
  const int tid = threadIdx.x;
  const float2* mlp = (const float2*)pml;
  #pragma unroll
  for (int i = 0; i < 3; ++i) {
    const int c = tid + i * 256;
    const int h = c >> 6;
    const float2 ml0 = mlp[(size_t)h * T_SEQ + q];
    const float2 ml1 = mlp[((size_t)NHEAD + h) * T_SEQ + q];
    const float M = fmaxf(ml0.x, ml1.x);
    const float w0 = expx(ml0.x - M), w1 = expx(ml1.x - M);
    const float inv = 1.0f / (ml0.y * w0 + ml1.y * w1);
    const float a0 = pacc[(size_t)q * C_EMBD + c];
    const float a1 = pacc[(size_t)T_SEQ * C_EMBD + (size_t)q * C_EMBD + c];
    out[(size_t)q * C_EMBD + c] = __float2bfloat16((a0 * w0 + a1 * w1) * inv);
  }
}

// ---------------------------------------------------------------- launch
extern "C" void kernel_launch(void* const* d_in, const int* in_sizes, int n_in,
                              void* d_out, int out_size, void* d_ws, size_t ws_size,
                              hipStream_t stream) {
  const float* x      = (const float*)d_in[0];
  const float* ln1_g  = (const float*)d_in[1];
  const float* ln1_b  = (const float*)d_in[2];
  const float* w_attn = (const float*)d_in[3];
  const float* b_attn = (const float*)d_in[4];
  const float* w_ao   = (const float*)d_in[5];
  const float* b_ao   = (const float*)d_in[6];
  const float* ln2_g  = (const float*)d_in[7];
  const float* ln2_b  = (const float*)d_in[8];
  const float* w_fc   = (const float*)d_in[9];
  const float* b_fc   = (const float*)d_in[10];
  const float* w_proj = (const float*)d_in[11];
  const float* b_proj = (const float*)d_in[12];

  char* ws = (char*)d_ws;
  size_t off = 0;
  auto alloc = [&](size_t nbytes) {
    char* p = ws + off;
    off += (nbytes + 255) & ~(size_t)255;
    return p;
  };
  bf16* wT_attn = (bf16*)alloc((size_t)C3 * C_EMBD * 2);        // [2304][768]
  bf16* wT_ao   = (bf16*)alloc((size_t)C_EMBD * C_EMBD * 2);    // [768][768]
  bf16* wT_fc   = (bf16*)alloc((size_t)4 * C_EMBD * C_EMBD * 2);// [3072][768]
  bf16* wT_proj = (bf16*)alloc((size_t)C_EMBD * 4 * C_EMBD * 2);// [768][3072]
  bf16* h       = (bf16*)alloc((size_t)T_SEQ * C_EMBD * 2);     // ln out (reused)
  bf16* qkv     = (bf16*)alloc((size_t)T_SEQ * C3 * 2);
  bf16* y       = (bf16*)alloc((size_t)T_SEQ * C_EMBD * 2);     // attn out
  float* x1     = (float*)alloc((size_t)T_SEQ * C_EMBD * 4);    // residual 1
  bf16* hf      = (bf16*)alloc((size_t)T_SEQ * 4 * C_EMBD * 2); // gelu out
  float* pml    = (float*)alloc((size_t)KVSPLIT * NHEAD * T_SEQ * 2 * 4); // (m,l) partials
  // Scratch lifetime plan (all aliases of buffers dead at time of use):
  //  - attn partials pacc -> hf (consumed by attn_combine, before ao GEMM)
  //  - ao split-K partials pa0/pa1 -> hf, hf+T*C floats (consumed by ln2_fused,
  //    then hf is rewritten by the fc GEMM)
  //  - proj split-K partials pp0 -> d_out, pp1 -> qkv (consumed by splitk_combine)
  float* pacc   = (float*)hf;
  float* pa0    = (float*)hf;
  float* pa1    = (float*)hf + (size_t)T_SEQ * C_EMBD;
  float* pp0    = (float*)d_out;
  float* pp1    = (float*)qkv;
  (void)ws_size; (void)in_sizes; (void)n_in; (void)out_size;

  // w_attn transpose + ln1 (only what the qkv GEMM needs)
  transpose1_ln_kernel<<<1728 + T_SEQ, 256, 0, stream>>>(w_attn, wT_attn, x, ln1_g, ln1_b, h);

  // qkv = h @ w_attn + b_attn  (bf16 out)
  gemm_bt<0><<<dim3(C3 / 128, T_SEQ / 128), 256, 0, stream>>>(h, wT_attn, b_attn, nullptr, qkv,
                                                              nullptr, T_SEQ, C3, C_EMBD, C_EMBD);
  // attention (768 blocks, XCD-chunked) + hidden transposes of w_ao/w_fc/w_proj (5184)
  attn_tr_kernel<<<768 + 5184, 256, 0, stream>>>(qkv, pacc, pml,
                                                 w_ao, wT_ao, w_fc, wT_fc, w_proj, wT_proj);
  attn_combine<<<T_SEQ, 256, 0, stream>>>(pacc, pml, y);
  // ao: split-K=2 deterministic partials (pa0/pa1 -> hf scratch)
  gemm_bt<4><<<dim3(C_EMBD / 128, T_SEQ / 128, 2), 256, 0, stream>>>(y, wT_ao, nullptr, nullptr,
                                                                     pa0, pa1, T_SEQ, C_EMBD,
                                                                     C_EMBD / 2, C_EMBD);
  // ln2 fused with ao combine: x1 = pa0+pa1+x+b_ao ; h = LN(x1)
  ln2_fused_kernel<<<T_SEQ, 256, 0, stream>>>(pa0, pa1, x, b_ao, ln2_g, ln2_b, h, x1);
  // hf = gelu(h @ w_fc + b_fc)  (bf16 out)
  gemm_bt<2><<<dim3(4 * C_EMBD / 128, T_SEQ / 128), 256, 0, stream>>>(h, wT_fc, b_fc, nullptr, hf,
                                                                      nullptr, T_SEQ, 4 * C_EMBD,
                                                                      C_EMBD, C_EMBD);
  // proj: split-K=2 deterministic partials (z0 -> d_out scratch, z1 -> qkv scratch)
  gemm_bt<4><<<dim3(C_EMBD / 128, T_SEQ / 128, 2), 256, 0, stream>>>(hf, wT_proj, nullptr, nullptr,
                                                                     pp0, pp1, T_SEQ, C_EMBD,
                                                                     2 * C_EMBD, 4 * C_EMBD);
  // out = p0 + p1 + x1 + b_proj
  splitk_combine<<<T_SEQ, 256, 0, stream>>>(pp0, pp1, x1, b_proj, (float*)d_out);
}